// Round 4
// baseline (552.721 us; speedup 1.0000x reference)
//
#include <hip/hip_runtime.h>
#include <hip/hip_bf16.h>
#include <stdint.h>

// ---------------------------------------------------------------------------
// AstrocyteMemoryModule r11: 5 launches.
//  L1 prep: converts (64B/thread) + W^T + combined bias + accum bias-init +
//           O/l zero + flag zero
//  L2 Wc = Wi@W (batched 1024^3, BK=32, 128^2 structure)
//  L3 gemm256: 256^2-tile, BK=32, 4-buffer depth-3 phase-split pipeline
//  L4 flash (no-max exp; atomicAdd unnormalized O partials + row-sums l)
//  L5 tail_fused: S1..S5 in ONE launch; inter-stage deps via device-scope
//     acquire/release flag counters; all 1280 blocks co-resident
//     (launch_bounds(256,5), LDS=0) => spins deadlock-free; each block
//     preloads its B-weights BEFORE spinning so weight traffic overlaps the
//     producer stage.
// ---------------------------------------------------------------------------

typedef __bf16 bf16;
typedef __bf16 bf16x4 __attribute__((ext_vector_type(4)));
typedef __bf16 bf16x8 __attribute__((ext_vector_type(8)));
typedef float f32x4 __attribute__((ext_vector_type(4)));

#define D_ 1024
#define M_ 8192
#define B_ 64
#define H_ 16

static __device__ __forceinline__ void gload16(const void* g, void* l) {
  __builtin_amdgcn_global_load_lds(
      (const __attribute__((address_space(1))) void*)g,
      (__attribute__((address_space(3))) void*)l, 16, 0, 0);
}

static __device__ __forceinline__ f32x4 mfma16(bf16x8 a, bf16x8 b, f32x4 c) {
  return __builtin_amdgcn_mfma_f32_16x16x32_bf16(a, b, c, 0, 0, 0);
}

// ---------------- thin GEMM (M=64): C = A @ B^T, reg-prefetched -------------
template <int U, int KLEN, typename OutT>
__device__ __forceinline__ void thin_gemm(
    const bf16* __restrict__ A, int lda,
    const bf16* __restrict__ Bm, int ldb,
    OutT* __restrict__ C, int ldc,
    const float* __restrict__ bias, float scale) {
  const int tid = threadIdx.x, lane = tid & 63, w = tid >> 6;
  const int rl = lane & 15, qq = lane >> 4;
  const bf16* pa = A + (int64_t)(w * 16 + rl) * lda + qq * 8;
  const bf16* pb[4];
  pb[0] = Bm + (int64_t)rl * ldb + qq * 8;
  pb[1] = pb[0] + (int64_t)16 * ldb;
  pb[2] = pb[0] + (int64_t)32 * ldb;
  pb[3] = pb[0] + (int64_t)48 * ldb;
  f32x4 acc[4] = {};
  bf16x8 av[2][U], bv[2][U][4];
#pragma unroll
  for (int u = 0; u < U; u++) {
    av[0][u] = *(const bf16x8*)(pa + u * 32);
#pragma unroll
    for (int j = 0; j < 4; j++)
      bv[0][u][j] = *(const bf16x8*)(pb[j] + u * 32);
  }
  constexpr int NI = KLEN / (32 * U);
#pragma unroll
  for (int it = 0; it < NI; it++) {
    const int cur = it & 1, nxt = cur ^ 1;
    if (it + 1 < NI) {
      int k = (it + 1) * 32 * U;
#pragma unroll
      for (int u = 0; u < U; u++) {
        av[nxt][u] = *(const bf16x8*)(pa + k + u * 32);
#pragma unroll
        for (int j = 0; j < 4; j++)
          bv[nxt][u][j] = *(const bf16x8*)(pb[j] + k + u * 32);
      }
    }
#pragma unroll
    for (int u = 0; u < U; u++)
#pragma unroll
      for (int j = 0; j < 4; j++)
        acc[j] = mfma16(av[cur][u], bv[cur][u][j], acc[j]);
  }
#pragma unroll
  for (int j = 0; j < 4; j++) {
    int gn = j * 16 + rl;
    float bb = bias ? bias[gn] : 0.0f;
#pragma unroll
    for (int r = 0; r < 4; r++) {
      int gm = w * 16 + qq * 4 + r;
      C[(int64_t)gm * ldc + gn] = (OutT)((acc[j][r] + bb) * scale);
    }
  }
}

// ------------------------------ prep (L1) ----------------------------------
// blocks: [0,7440) cvt (64B/thread), [7440,10512) W^T, [10512,11280) bias-
// combine, [11280,11664) accum bias-init, [11664,11728) O/l zero + flags
struct CvtD { const float* src; bf16* dst; int end; };  // end in 16-float units
struct PrepArgs {
  CvtD d[9];
  const float *Wq, *Wk, *Wv, *inw, *inb, *bq, *bk, *bv;
  const float *outb, *gb1, *gb2, *ib1, *ib2;
  bf16* WT;
  float *bc, *msR, *g1R, *gateR, *h1R, *out, *Oraw, *lmat;
  uint32_t* flags;
};

__global__ __launch_bounds__(256) void prep_kernel(PrepArgs a) {
  const int bx = blockIdx.x, tid = threadIdx.x;
  if (bx < 7440) {
    int g = bx * 256 + tid;  // 16-float unit index
    CvtD dd = a.d[8];
    int begin = a.d[7].end;
#pragma unroll
    for (int t = 7; t >= 0; t--)
      if (g < a.d[t].end) { dd = a.d[t]; begin = t ? a.d[t - 1].end : 0; }
    int i = (g - begin) * 16;
#pragma unroll
    for (int u = 0; u < 4; u++) {
      float4 v = *(const float4*)(dd.src + i + u * 4);
      bf16x4 o = { (bf16)v.x, (bf16)v.y, (bf16)v.z, (bf16)v.w };
      *(bf16x4*)(dd.dst + i + u * 4) = o;
    }
  } else if (bx < 10512) {
    int t = bx - 7440;
    int z = t >> 10, rem = t & 1023;
    const float* src = z == 0 ? a.Wq : z == 1 ? a.Wk : a.Wv;
    bf16* out = a.WT + (int64_t)z * D_ * D_;
    __shared__ bf16 tile[32][33];
    int tx = tid & 31, ty = tid >> 5;
    int r0 = (rem >> 5) * 32, c0 = (rem & 31) * 32;
#pragma unroll
    for (int i = 0; i < 32; i += 8)
      tile[ty + i][tx] = (bf16)src[(int64_t)(r0 + ty + i) * D_ + c0 + tx];
    __syncthreads();
#pragma unroll
    for (int i = 0; i < 32; i += 8)
      out[(int64_t)(c0 + ty + i) * D_ + r0 + tx] = tile[tx][ty + i];
  } else if (bx < 11280) {
    int t = bx - 10512;
    int w = tid >> 6, lane = tid & 63;
    int ng = t * 4 + w;  // [0, 3072)
    int z = ng >> 10;
    const float* Wi = a.inw + (int64_t)ng * D_;
    const float* b = z == 0 ? a.bq : z == 1 ? a.bk : a.bv;
    float acc = 0.f;
#pragma unroll
    for (int l = 0; l < D_; l += 64) acc += Wi[l + lane] * b[l + lane];
#pragma unroll
    for (int m = 32; m; m >>= 1) acc += __shfl_xor(acc, m, 64);
    if (lane == 0) a.bc[ng] = acc + a.inb[ng];
  } else if (bx < 11664) {
    int t = bx - 11280;           // [0, 384)
    int seg = t >> 6, row = t & 63;
    int n = tid * 4;              // [0, 1024)
    const float* b;
    float* dst;
    int bn = n;
    if (seg == 0)      { dst = a.msR   + row * 1024;        b = a.outb; }
    else if (seg == 1) { dst = a.g1R   + row * 1024;        b = a.gb1;  }
    else if (seg == 2) { dst = a.gateR + row * 1024;        b = a.gb2;  }
    else if (seg == 3) { dst = a.h1R   + row * 2048;        b = a.ib1;  }
    else if (seg == 4) { dst = a.h1R   + row * 2048 + 1024; b = a.ib1; bn = 1024 + n; }
    else               { dst = a.out   + row * 1024;        b = a.ib2;  }
    *(float4*)(dst + n) = *(const float4*)(b + bn);
  } else {
    int b = bx - 11664;           // [0, 64): O/l zero + flags
    float4 z4 = {0.f, 0.f, 0.f, 0.f};
    *(float4*)(a.Oraw + b * 1024 + tid * 4) = z4;
    if (b < 16 && tid < 64) a.lmat[b * 64 + tid] = 0.f;
    if (b == 0 && tid < 16) a.flags[tid] = 0u;
  }
}

// ------------------------- big GEMM: C = A @ B^T (BK=32) -------------------
// (kept for L2 only: MODE 0)
template <int MODE>
__global__ __launch_bounds__(256) void gemm_big(
    const bf16* __restrict__ A, int lda, int64_t sA,
    const bf16* __restrict__ Bm, int ldb, int64_t sB,
    bf16* __restrict__ C, int ldc, int64_t sC, bf16* __restrict__ Ct,
    const float* __restrict__ bias, int64_t sbias, int K,
    const bf16* __restrict__ qA, const bf16* __restrict__ qB,
    bf16* __restrict__ qC, const float* __restrict__ qbias) {
  int m0, n0, z;
  if (MODE == 0) {
    z = blockIdx.z; m0 = blockIdx.y * 128; n0 = blockIdx.x * 128;
  } else {
    if ((int)blockIdx.x >= 1024) {
      int n0q = ((int)blockIdx.x - 1024) * 64;
      thin_gemm<2, 1024, bf16>(qA, D_, qB + (int64_t)n0q * D_, D_,
                               qC + n0q, D_, qbias + n0q, 0.125f);
      return;
    }
    int lin = blockIdx.x, xcd = lin & 7, slot = lin >> 3;
    z = slot >> 6;
    int r = slot & 63;
    m0 = (xcd * 8 + (r >> 3)) * 128;
    n0 = (r & 7) * 128;
  }
  A += (int64_t)z * sA; Bm += (int64_t)z * sB;
  if (bias) bias += (int64_t)z * sbias;
  __shared__ alignas(16) bf16 As[128 * 32];
  __shared__ alignas(16) bf16 Bs[128 * 32];
  const int tid = threadIdx.x, lane = tid & 63, w = tid >> 6;
  const int wm = (w & 1) * 64, wn = (w >> 1) * 64;
  const int rl = lane & 15, qq = lane >> 4;
  f32x4 acc[4][4] = {};

  int c0 = w * 64 + lane, c1 = (4 + w) * 64 + lane;
  int ra0 = c0 >> 2, qa0 = (c0 & 3) ^ ((ra0 >> 1) & 3);
  int ra1 = c1 >> 2, qa1 = (c1 & 3) ^ ((ra1 >> 1) & 3);
  const bf16* gA0 = A + (int64_t)(m0 + ra0) * lda + qa0 * 8;
  const bf16* gA1 = A + (int64_t)(m0 + ra1) * lda + qa1 * 8;
  const bf16* gB0 = Bm + (int64_t)(n0 + ra0) * ldb + qa0 * 8;
  const bf16* gB1 = Bm + (int64_t)(n0 + ra1) * ldb + qa1 * 8;
  bf16* lA0 = As + w * 512;
  bf16* lA1 = As + (4 + w) * 512;
  bf16* lB0 = Bs + w * 512;
  bf16* lB1 = Bs + (4 + w) * 512;

  for (int k0 = 0; k0 < K; k0 += 32) {
    __syncthreads();
    gload16(gA0 + k0, lA0);
    gload16(gA1 + k0, lA1);
    gload16(gB0 + k0, lB0);
    gload16(gB1 + k0, lB1);
    __syncthreads();
    bf16x8 af[4], bb[4];
#pragma unroll
    for (int i = 0; i < 4; i++) {
      int r = wm + i * 16 + rl;
      af[i] = *(const bf16x8*)(As + r * 32 + (qq ^ ((r >> 1) & 3)) * 8);
    }
#pragma unroll
    for (int j = 0; j < 4; j++) {
      int r = wn + j * 16 + rl;
      bb[j] = *(const bf16x8*)(Bs + r * 32 + (qq ^ ((r >> 1) & 3)) * 8);
    }
#pragma unroll
    for (int i = 0; i < 4; i++)
#pragma unroll
      for (int j = 0; j < 4; j++)
        acc[i][j] = mfma16(af[i], bb[j], acc[i][j]);
  }
  if (MODE == 1 && z == 1) {
#pragma unroll
    for (int j = 0; j < 4; j++) {
      int gn = n0 + wn + j * 16 + rl;
      float bb2 = bias ? bias[gn] : 0.0f;
#pragma unroll
      for (int i = 0; i < 4; i++) {
        int gm0 = m0 + wm + i * 16 + qq * 4;
        f32x4 a = acc[i][j];
        bf16x4 o = { (bf16)(a[0] + bb2), (bf16)(a[1] + bb2),
                     (bf16)(a[2] + bb2), (bf16)(a[3] + bb2) };
        *(bf16x4*)(Ct + (int64_t)gn * M_ + gm0) = o;
      }
    }
  } else {
    C += (int64_t)z * sC;
#pragma unroll
    for (int j = 0; j < 4; j++) {
      int gn = n0 + wn + j * 16 + rl;
      float bb2 = bias ? bias[gn] : 0.0f;
#pragma unroll
      for (int i = 0; i < 4; i++) {
        int gm0 = m0 + wm + i * 16 + qq * 4;
#pragma unroll
        for (int r = 0; r < 4; r++)
          C[(int64_t)(gm0 + r) * ldc + gn] = (bf16)(acc[i][j][r] + bb2);
      }
    }
  }
}

// ----------------- L3: 256^2-tile phase-split GEMM (kh + vhT) --------------
__global__ __launch_bounds__(512) void gemm256(
    const bf16* __restrict__ A,    // mkmv (z=0: mk, z=1: mv)
    const bf16* __restrict__ Wc,   // Wc base; +D*D = Wc_k, +2D*D = Wc_v
    const float* __restrict__ bc,  // combined bias; +D = bik, +2D = biv
    bf16* __restrict__ kh, bf16* __restrict__ vhT,
    const bf16* __restrict__ qA, const bf16* __restrict__ qB,
    bf16* __restrict__ qC, const float* __restrict__ qbias) {
  extern __shared__ __align__(16) bf16 lds[];  // 4 * (8192 A + 8192 B) bf16
  const int bid = blockIdx.x;
  if (bid >= 256) {  // thin qh blocks at grid tail
    if (threadIdx.x < 256) {
      int n0q = (bid - 256) * 64;
      thin_gemm<2, 1024, bf16>(qA, D_, qB + (int64_t)n0q * D_, D_,
                               qC + n0q, D_, qbias + n0q, 0.125f);
    }
    return;
  }
  const int lin = bid;
  const int xcd = lin & 7, s = lin >> 3;
  const int z = xcd >> 2;
  const int m0 = ((xcd & 3) * 8 + (s >> 2)) * 256;
  const int n0 = (s & 3) * 256;
  const bf16* Ab = A + (int64_t)z * M_ * D_;
  const bf16* Bb = Wc + (int64_t)(z + 1) * D_ * D_;
  const float* bias = bc + (z + 1) * D_;

  const int tid = threadIdx.x, lane = tid & 63, w = tid >> 6;
  const int rl = lane & 15, qq = lane >> 4;
  const int wr = w >> 2, wcn = w & 3;

  const int ci0 = w * 128 + lane, ci1 = ci0 + 64;
  const int ra0 = ci0 >> 2, ca0 = (ci0 & 3) ^ ((ra0 >> 1) & 3);
  const int ra1 = ci1 >> 2, ca1 = (ci1 & 3) ^ ((ra1 >> 1) & 3);
  const bf16* gA0 = Ab + (int64_t)(m0 + ra0) * D_ + ca0 * 8;
  const bf16* gA1 = Ab + (int64_t)(m0 + ra1) * D_ + ca1 * 8;
  const bf16* gB0 = Bb + (int64_t)(n0 + ra0) * D_ + ca0 * 8;
  const bf16* gB1 = Bb + (int64_t)(n0 + ra1) * D_ + ca1 * 8;
  const int lA0 = w * 1024, lA1 = lA0 + 512;

  f32x4 acc[8][4] = {};
  bf16x8 bfr[4], afr[4];
  const int sq8 = (qq ^ ((rl >> 1) & 3)) * 8;

#define SCB __builtin_amdgcn_sched_barrier(0)
#define BARR __builtin_amdgcn_s_barrier()
#define VMW(N) asm volatile("s_waitcnt vmcnt(" #N ")")

#define STAGE_FULL(BUF, KT)                          \
  do {                                               \
    bf16* bse_ = lds + (BUF) * 16384;                \
    gload16(gA0 + (KT) * 32, bse_ + lA0);            \
    gload16(gA1 + (KT) * 32, bse_ + lA1);            \
    gload16(gB0 + (KT) * 32, bse_ + 8192 + lA0);     \
    gload16(gB1 + (KT) * 32, bse_ + 8192 + lA1);     \
  } while (0)

#define PH_A(BUF, DOSTAGE, SKT)                                              \
  do {                                                                       \
    const bf16* ba_ = lds + (BUF) * 16384;                                   \
    const bf16* bb_ = ba_ + 8192;                                            \
    for (int j = 0; j < 4; j++)                                              \
      bfr[j] = *(const bf16x8*)(bb_ + (wcn * 64 + j * 16 + rl) * 32 + sq8);  \
    for (int mi = 0; mi < 4; mi++)                                           \
      afr[mi] = *(const bf16x8*)(ba_ + (wr * 128 + mi * 16 + rl) * 32 + sq8);\
    if (DOSTAGE) {                                                           \
      bf16* bse_ = lds + ((SKT) & 3) * 16384;                                \
      gload16(gA0 + (SKT) * 32, bse_ + lA0);                                 \
      gload16(gA1 + (SKT) * 32, bse_ + lA1);                                 \
    }                                                                        \
    SCB; BARR; SCB;                                                          \
    __builtin_amdgcn_s_setprio(1);                                           \
    for (int mi = 0; mi < 4; mi++)                                           \
      for (int j = 0; j < 4; j++)                                            \
        acc[mi][j] = mfma16(afr[mi], bfr[j], acc[mi][j]);                    \
    __builtin_amdgcn_s_setprio(0);                                           \
    SCB; BARR; SCB;                                                          \
  } while (0)

#define PH_B(BUF, DOSTAGE, SKT, VMSTMT)                                      \
  do {                                                                       \
    const bf16* ba_ = lds + (BUF) * 16384;                                   \
    for (int mi = 0; mi < 4; mi++)                                           \
      afr[mi] =                                                              \
          *(const bf16x8*)(ba_ + (wr * 128 + (mi + 4) * 16 + rl) * 32 + sq8);\
    if (DOSTAGE) {                                                           \
      bf16* bse_ = lds + ((SKT) & 3) * 16384;                                \
      gload16(gB0 + (SKT) * 32, bse_ + 8192 + lA0);                          \
      gload16(gB1 + (SKT) * 32, bse_ + 8192 + lA1);                          \
    }                                                                        \
    VMSTMT;                                                                  \
    SCB; BARR; SCB;                                                          \
    __builtin_amdgcn_s_setprio(1);                                           \
    for (int mi = 0; mi < 4; mi++)                                           \
      for (int j = 0; j < 4; j++)                                            \
        acc[mi + 4][j] = mfma16(afr[mi], bfr[j], acc[mi + 4][j]);            \
    __builtin_amdgcn_s_setprio(0);                                           \
    SCB; BARR; SCB;                                                          \
  } while (0)

  STAGE_FULL(0, 0);
  STAGE_FULL(1, 1);
  STAGE_FULL(2, 2);
  VMW(8);
  SCB; BARR; SCB;

#pragma unroll 1
  for (int t = 0; t < 7; t++) {
    const int kb = t * 4;
    PH_A(0, 1, kb + 3); PH_B(0, 1, kb + 3, VMW(8));
    PH_A(1, 1, kb + 4); PH_B(1, 1, kb + 4, VMW(8));
    PH_A(2, 1, kb + 5); PH_B(2, 1, kb + 5, VMW(8));
    PH_A(3, 1, kb + 6); PH_B(3, 1, kb + 6, VMW(8));
  }
  PH_A(0, 1, 31); PH_B(0, 1, 31, VMW(8));
  PH_A(1, 0, 0);  PH_B(1, 0, 0, VMW(4));
  PH_A(2, 0, 0);  PH_B(2, 0, 0, VMW(0));
  PH_A(3, 0, 0);  PH_B(3, 0, 0, (void)0);

#undef SCB
#undef BARR
#undef VMW
#undef STAGE_FULL
#undef PH_A
#undef PH_B

  if (z == 0) {
#pragma unroll
    for (int j = 0; j < 4; j++) {
      int gn = n0 + wcn * 64 + j * 16 + rl;
      float bb2 = bias[gn];
#pragma unroll
      for (int mi = 0; mi < 8; mi++) {
        int gm0 = m0 + wr * 128 + mi * 16 + qq * 4;
#pragma unroll
        for (int r = 0; r < 4; r++)
          kh[(int64_t)(gm0 + r) * D_ + gn] = (bf16)(acc[mi][j][r] + bb2);
      }
    }
  } else {
#pragma unroll
    for (int j = 0; j < 4; j++) {
      int gn = n0 + wcn * 64 + j * 16 + rl;
      float bb2 = bias[gn];
#pragma unroll
      for (int mi = 0; mi < 8; mi++) {
        int gm0 = m0 + wr * 128 + mi * 16 + qq * 4;
        f32x4 a = acc[mi][j];
        bf16x4 o = { (bf16)(a[0] + bb2), (bf16)(a[1] + bb2),
                     (bf16)(a[2] + bb2), (bf16)(a[3] + bb2) };
        *(bf16x4*)(vhT + (int64_t)gn * M_ + gm0) = o;
      }
    }
  }
}

// --------------------------- flash, no-max (L4) ----------------------------
__global__ __launch_bounds__(256, 2) void flash_kernel(
    const bf16* __restrict__ qh, const bf16* __restrict__ kh,
    const bf16* __restrict__ vhT, float* __restrict__ Oraw,
    float* __restrict__ lmat) {
  const int tid = threadIdx.x, lane = tid & 63, w = tid >> 6;
  const int rl = lane & 15, qq = lane >> 4;
  const int h = blockIdx.x >> 4, c = blockIdx.x & 15;
  __shared__ alignas(16) bf16 Plds[4 * 16 * 72];
  const bf16* qhp = qh + (int64_t)(w * 16 + rl) * D_ + h * 64 + qq * 8;
  bf16x8 aq0 = *(const bf16x8*)(qhp);
  bf16x8 aq1 = *(const bf16x8*)(qhp + 32);
  float lsum[4] = {0.f, 0.f, 0.f, 0.f};
  f32x4 acc_o[4] = {};
  bf16* pl = Plds + w * 1152;
  const bf16* khb = kh + (int64_t)(c * 512) * D_ + h * 64 + qq * 8;
  const bf16* vtb = vhT + (int64_t)(h * 64) * M_ + c * 512 + qq * 8;
  for (int nt = 0; nt < 8; nt++) {
    int mb = nt * 64;
    bf16x8 bk0[4], bk1[4], vv0[4], vv1[4];
#pragma unroll
    for (int j = 0; j < 4; j++) {
      const bf16* p = khb + (int64_t)(mb + j * 16 + rl) * D_;
      bk0[j] = *(const bf16x8*)(p);
      bk1[j] = *(const bf16x8*)(p + 32);
      const bf16* q = vtb + (int64_t)(j * 16 + rl) * M_ + mb;
      vv0[j] = *(const bf16x8*)(q);
      vv1[j] = *(const bf16x8*)(q + 32);
    }
    f32x4 s[4] = {};
#pragma unroll
    for (int j = 0; j < 4; j++) {
      s[j] = mfma16(aq0, bk0[j], s[j]);
      s[j] = mfma16(aq1, bk1[j], s[j]);
    }
#pragma unroll
    for (int j = 0; j < 4; j++)
#pragma unroll
      for (int r = 0; r < 4; r++) {
        float p = __expf(s[j][r]);
        lsum[r] += p;
        pl[(qq * 4 + r) * 72 + j * 16 + rl] = (bf16)p;
      }
    bf16x8 pa0 = *(const bf16x8*)(pl + rl * 72 + qq * 8);
    bf16x8 pa1 = *(const bf16x8*)(pl + rl * 72 + 32 + qq * 8);
#pragma unroll
    for (int j = 0; j < 4; j++) {
      acc_o[j] = mfma16(pa0, vv0[j], acc_o[j]);
      acc_o[j] = mfma16(pa1, vv1[j], acc_o[j]);
    }
  }
#pragma unroll
  for (int msk = 1; msk <= 8; msk <<= 1)
#pragma unroll
    for (int r = 0; r < 4; r++) lsum[r] += __shfl_xor(lsum[r], msk, 64);
#pragma unroll
  for (int j = 0; j < 4; j++)
#pragma unroll
    for (int r = 0; r < 4; r++)
      atomicAdd(&Oraw[(int64_t)(w * 16 + qq * 4 + r) * D_ + h * 64 + j * 16 + rl],
                acc_o[j][r]);
  if (rl == 0)
#pragma unroll
    for (int r = 0; r < 4; r++)
      atomicAdd(&lmat[h * 64 + w * 16 + qq * 4 + r], lsum[r]);
}

// ---------------------- fused tail: S1..S5 one launch ----------------------
// grid 1280 x 256 thr, launch_bounds(256,5) => VGPR<=102, LDS=0 => all
// blocks co-resident => flag spins deadlock-free.
// bid: [0,128) S1 | [128,384) S2 | [384,512) S3 | [512,1024) S4 | [1024,) S5
// flags: [0]=S1 done-count, [1]=S2, [2]=S3, [3]=S4.
// Each block: compute B-ptrs + PRELOAD 16KB weights -> spin -> A/activation
// loads -> 16 MFMA -> atomicAdd C -> signal.
__global__ __launch_bounds__(256, 5) void tail_fused(
    const float* __restrict__ Oraw, const float* __restrict__ lmat,
    const bf16* __restrict__ xbf, float* __restrict__ msR,
    float* __restrict__ g1R, float* __restrict__ gateR,
    float* __restrict__ h1R, float* __restrict__ out,
    const bf16* __restrict__ outwb, const bf16* __restrict__ gW1b,
    const bf16* __restrict__ gW2b, const bf16* __restrict__ iW1b,
    const bf16* __restrict__ iW2b, uint32_t* __restrict__ flags) {
  const int bid = blockIdx.x;
  const int tid = threadIdx.x, lane = tid & 63, w = tid >> 6;
  const int rl = lane & 15, qq = lane >> 4;
  const int m = w * 16 + rl;

  int stage, local;
  if (bid < 128)       { stage = 0; local = bid; }
  else if (bid < 384)  { stage = 1; local = bid - 128; }
  else if (bid < 512)  { stage = 2; local = bid - 384; }
  else if (bid < 1024) { stage = 3; local = bid - 512; }
  else                 { stage = 4; local = bid - 1024; }

  int n0, kc;
  if (stage == 3) { n0 = (local & 31) * 64; kc = local >> 5; }
  else            { n0 = (local & 15) * 64; kc = local >> 4; }
  const int bk0 = kc * 128;

  const bf16* Bw; int ldb; float* Craw; int ldc;
  const float* p0f = nullptr; const bf16* p0b = nullptr;
  const float* p1f = nullptr; int lda; int kind;
  int spin = -1, starget = 0, sig;
  switch (stage) {
    case 0:
      Bw = outwb; ldb = D_; Craw = msR; ldc = D_;
      p0f = Oraw + bk0; p1f = lmat; lda = D_; kind = 4; sig = 0;
      break;
    case 1:
      Bw = gW1b; ldb = 2 * D_; Craw = g1R; ldc = D_; sig = 1;
      if (kc < 8) { p0b = xbf + bk0; lda = D_; kind = 0; }
      else { p0f = msR + (kc - 8) * 128; lda = D_; kind = 1;
             spin = 0; starget = 128; }
      break;
    case 2:
      Bw = gW2b; ldb = D_; Craw = gateR; ldc = D_;
      p0f = g1R + bk0; lda = D_; kind = 2; spin = 1; starget = 256; sig = 2;
      break;
    case 3:
      Bw = iW1b; ldb = 2 * D_; Craw = h1R; ldc = 2 * D_; sig = 3;
      if (kc < 8) { p0b = xbf + bk0; lda = D_; kind = 0; }
      else { p0f = gateR + (kc - 8) * 128; p1f = msR + (kc - 8) * 128;
             lda = D_; kind = 3; spin = 2; starget = 128; }
      break;
    default:
      Bw = iW2b; ldb = 2 * D_; Craw = out; ldc = D_;
      p0f = h1R + bk0; lda = 2 * D_; kind = 2; spin = 3; starget = 512;
      sig = -1;
      break;
  }

  // weight preload (independent of producer stages)
  const bf16* pb[4];
#pragma unroll
  for (int j = 0; j < 4; j++)
    pb[j] = Bw + (int64_t)(n0 + j * 16 + rl) * ldb + bk0 + qq * 8;
  bf16x8 bw[4][4];
#pragma unroll
  for (int kk = 0; kk < 4; kk++)
#pragma unroll
    for (int j = 0; j < 4; j++) bw[kk][j] = *(const bf16x8*)(pb[j] + kk * 32);

  if (spin >= 0) {
    if (tid == 0) {
      while (__hip_atomic_load(&flags[spin], __ATOMIC_ACQUIRE,
                               __HIP_MEMORY_SCOPE_AGENT) < (uint32_t)starget)
        __builtin_amdgcn_s_sleep(2);
    }
    __syncthreads();
  }

  f32x4 acc[4] = {};
#pragma unroll
  for (int kk = 0; kk < 4; kk++) {
    bf16x8 af;
    if (kind == 0) {
      af = *(const bf16x8*)(p0b + (int64_t)m * lda + kk * 32 + qq * 8);
    } else {
      const float* p = p0f + (int64_t)m * lda + kk * 32 + qq * 8;
      float4 u0 = *(const float4*)p;
      float4 u1 = *(const float4*)(p + 4);
      if (kind == 2) {
        u0.x = fmaxf(u0.x, 0.f); u0.y = fmaxf(u0.y, 0.f);
        u0.z = fmaxf(u0.z, 0.f); u0.w = fmaxf(u0.w, 0.f);
        u1.x = fmaxf(u1.x, 0.f); u1.y = fmaxf(u1.y, 0.f);
        u1.z = fmaxf(u1.z, 0.f); u1.w = fmaxf(u1.w, 0.f);
      } else if (kind == 3) {
        const float* pm = p1f + (int64_t)m * lda + kk * 32 + qq * 8;
        float4 m0 = *(const float4*)pm;
        float4 m1 = *(const float4*)(pm + 4);
        u0.x = m0.x / (1.f + __expf(-u0.x)); u0.y = m0.y / (1.f + __expf(-u0.y));
        u0.z = m0.z / (1.f + __expf(-u0.z)); u0.w = m0.w / (1.f + __expf(-u0.w));
        u1.x = m1.x / (1.f + __expf(-u1.x)); u1.y = m1.y / (1.f + __expf(-u1.y));
        u1.z = m1.z / (1.f + __expf(-u1.z)); u1.w = m1.w / (1.f + __expf(-u1.w));
      } else if (kind == 4) {
        int hidx = (bk0 + kk * 32) >> 6;
        float linv = 1.0f / p1f[hidx * 64 + m];
        u0.x *= linv; u0.y *= linv; u0.z *= linv; u0.w *= linv;
        u1.x *= linv; u1.y *= linv; u1.z *= linv; u1.w *= linv;
      }
      af = (bf16x8){ (bf16)u0.x, (bf16)u0.y, (bf16)u0.z, (bf16)u0.w,
                     (bf16)u1.x, (bf16)u1.y, (bf16)u1.z, (bf16)u1.w };
    }
#pragma unroll
    for (int j = 0; j < 4; j++) acc[j] = mfma16(af, bw[kk][j], acc[j]);
  }
#pragma unroll
  for (int j = 0; j < 4; j++) {
    int gn = n0 + j * 16 + rl;
#pragma unroll
    for (int r = 0; r < 4; r++) {
      int gm = w * 16 + qq * 4 + r;
      atomicAdd(&Craw[(int64_t)gm * ldc + gn], acc[j][r]);
    }
  }
  if (sig >= 0) {
    __syncthreads();  // per-wave vmcnt(0) drain before barrier => atomics done
    if (tid == 0)
      __hip_atomic_fetch_add(&flags[sig], 1u, __ATOMIC_RELEASE,
                             __HIP_MEMORY_SCOPE_AGENT);
  }
}

// ------------------------------- launch ------------------------------------
extern "C" void kernel_launch(void* const* d_in, const int* in_sizes, int n_in,
                              void* d_out, int out_size, void* d_ws,
                              size_t ws_size, hipStream_t stream) {
  (void)in_sizes; (void)n_in; (void)out_size;
  const float* x    = (const float*)d_in[0];
  const float* mk   = (const float*)d_in[1];
  const float* mv   = (const float*)d_in[2];
  const float* Wq   = (const float*)d_in[3];
  const float* bq   = (const float*)d_in[4];
  const float* Wk   = (const float*)d_in[5];
  const float* bk   = (const float*)d_in[6];
  const float* Wv   = (const float*)d_in[7];
  const float* bv   = (const float*)d_in[8];
  const float* inw  = (const float*)d_in[9];
  const float* inb  = (const float*)d_in[10];
  const float* outw = (const float*)d_in[11];
  const float* outb = (const float*)d_in[12];
  const float* gW1  = (const float*)d_in[13];
  const float* gb1  = (const float*)d_in[14];
  const float* gW2  = (const float*)d_in[15];
  const float* gb2  = (const float*)d_in[16];
  const float* iW1  = (const float*)d_in[17];
  const float* ib1  = (const float*)d_in[18];
  const float* iW2  = (const float*)d_in[19];
  const float* ib2  = (const float*)d_in[20];

  char* ws = (char*)d_ws;
  size_t off = 0;
  auto alloc = [&](size_t bytes) {
    char* p = ws + off;
    off += (bytes + 255) & ~(size_t)255;
    return p;
  };
  bf16* mkmv  = (bf16*)alloc((size_t)2 * M_ * D_ * 2);
  bf16* inpj  = (bf16*)alloc((size_t)3 * D_ * D_ * 2);
  bf16* WT    = (bf16*)alloc((size_t)3 * D_ * D_ * 2);
  bf16* Wc    = (bf16*)alloc((size_t)3 * D_ * D_ * 2);
  float* bc   = (float*)alloc(3 * D_ * 4);
  bf16* xbf   = (bf16*)alloc((size_t)B_ * D_ * 2);
  bf16* qh    = (bf16*)alloc((size_t)B_ * D_ * 2);
  bf16* kh    = (bf16*)alloc((size_t)M_ * D_ * 2);
  bf16* vhT   = (bf16*)alloc((size_t)M_ * D_ * 2);
  float* Oraw = (float*)alloc((size_t)B_ * D_ * 4);
  float* lmat = (float*)alloc((size_t)H_ * B_ * 4);
  float* msR  = (float*)alloc((size_t)B_ * D_ * 4);
  float* g1R  = (float*)alloc((size_t)B_ * D_ * 4);
  float* gateR= (float*)alloc((size_t)B_ * D_ * 4);
  float* h1R  = (float*)alloc((size_t)B_ * 2 * D_ * 4);
  bf16* gW1b  = (bf16*)alloc((size_t)D_ * 2 * D_ * 2);
  bf16* gW2b  = (bf16*)alloc((size_t)D_ * D_ * 2);
  bf16* iW1b  = (bf16*)alloc((size_t)2 * D_ * 2 * D_ * 2);
  bf16* iW2b  = (bf16*)alloc((size_t)D_ * 2 * D_ * 2);
  bf16* outwb = (bf16*)alloc((size_t)D_ * D_ * 2);
  uint32_t* flags = (uint32_t*)alloc(64);
  if (ws_size < off) return;

  // L1: prep  (cvt ends in 16-float units)
  PrepArgs pa;
  pa.d[0] = { mk,   mkmv,           524288 };
  pa.d[1] = { mv,   mkmv + M_ * D_, 1048576 };
  pa.d[2] = { inw,  inpj,           1245184 };
  pa.d[3] = { gW1,  gW1b,           1376256 };
  pa.d[4] = { gW2,  gW2b,           1441792 };
  pa.d[5] = { iW1,  iW1b,           1703936 };
  pa.d[6] = { iW2,  iW2b,           1835008 };
  pa.d[7] = { outw, outwb,          1900544 };
  pa.d[8] = { x,    xbf,            1904640 };
  pa.Wq = Wq; pa.Wk = Wk; pa.Wv = Wv; pa.inw = inw; pa.inb = inb;
  pa.bq = bq; pa.bk = bk; pa.bv = bv;
  pa.outb = outb; pa.gb1 = gb1; pa.gb2 = gb2; pa.ib1 = ib1; pa.ib2 = ib2;
  pa.WT = WT; pa.bc = bc; pa.msR = msR; pa.g1R = g1R; pa.gateR = gateR;
  pa.h1R = h1R; pa.out = (float*)d_out; pa.Oraw = Oraw; pa.lmat = lmat;
  pa.flags = flags;
  prep_kernel<<<dim3(11728), 256, 0, stream>>>(pa);

  // L2: Wc_z = Wi_z @ W_z
  gemm_big<0><<<dim3(8, 8, 3), 256, 0, stream>>>(
      inpj, D_, (int64_t)D_ * D_, WT, D_, (int64_t)D_ * D_,
      Wc, D_, (int64_t)D_ * D_, nullptr, nullptr, 0, D_,
      nullptr, nullptr, nullptr, nullptr);

  // L3: kh / vhT via phase-split 256^2 kernel (+ qh thin blocks at grid tail)
  hipFuncSetAttribute((const void*)gemm256,
                      hipFuncAttributeMaxDynamicSharedMemorySize, 131072);
  gemm256<<<dim3(272), dim3(512), 131072, stream>>>(
      mkmv, Wc, bc, kh, vhT, xbf, Wc, qh, bc);

  // L4: flash partials -> atomic Oraw / lmat
  flash_kernel<<<dim3(256), 256, 0, stream>>>(qh, kh, vhT, Oraw, lmat);

  // L5: fused tail S1..S5 (flag-synced single launch)
  tail_fused<<<dim3(1280), 256, 0, stream>>>(
      Oraw, lmat, xbf, msR, g1R, gateR, h1R, (float*)d_out,
      outwb, gW1b, gW2b, iW1b, iW2b, flags);
}

// Round 5
// 359.984 us; speedup vs baseline: 1.5354x; 1.5354x over previous
//
#include <hip/hip_runtime.h>
#include <hip/hip_bf16.h>
#include <stdint.h>

// ---------------------------------------------------------------------------
// AstrocyteMemoryModule r12: 10 launches.
//  L1 prep: converts (64B/thread, incl. Wq->bf16) + W^T (k,v only) +
//           combined bias + accum bias-init + O/l zero
//  L2 gemm_l2: split-K x4 Wc partials for k,v (512 blocks = 2/CU, 128^2
//           tile, K=256/block, fp32 partial stores - no atomics) + 16 thin
//           blocks computing q1 = x @ Wq^T
//  L3 cvt_wc: sum 4 partials -> bf16 Wc (k,v slots). Partials ALIAS kh/vhT
//           (overwritten only after this kernel retires).
//  L4 gemm256: 256^2-tile phase-split pipeline (kh, vhT) + thin blocks
//           qh = q1 @ Wiq^T + bc_q (numerically == old path: one bf16
//           intermediate rounding either way)
//  L5 flash (no-max exp; atomicAdd unnormalized O partials + row-sums l)
//  L6-L10 tail stages: split-K atomic GEMMs (restored r9 structure; the
//           spin-fused variant measured 244 us - reverted)
// ---------------------------------------------------------------------------

typedef __bf16 bf16;
typedef __bf16 bf16x4 __attribute__((ext_vector_type(4)));
typedef __bf16 bf16x8 __attribute__((ext_vector_type(8)));
typedef float f32x4 __attribute__((ext_vector_type(4)));

#define D_ 1024
#define M_ 8192
#define B_ 64
#define H_ 16

static __device__ __forceinline__ void gload16(const void* g, void* l) {
  __builtin_amdgcn_global_load_lds(
      (const __attribute__((address_space(1))) void*)g,
      (__attribute__((address_space(3))) void*)l, 16, 0, 0);
}

static __device__ __forceinline__ f32x4 mfma16(bf16x8 a, bf16x8 b, f32x4 c) {
  return __builtin_amdgcn_mfma_f32_16x16x32_bf16(a, b, c, 0, 0, 0);
}

// ---------------- thin GEMM (M=64): C = A @ B^T, reg-prefetched -------------
template <int U, int KLEN, typename OutT>
__device__ __forceinline__ void thin_gemm(
    const bf16* __restrict__ A, int lda,
    const bf16* __restrict__ Bm, int ldb,
    OutT* __restrict__ C, int ldc,
    const float* __restrict__ bias, float scale) {
  const int tid = threadIdx.x, lane = tid & 63, w = tid >> 6;
  const int rl = lane & 15, qq = lane >> 4;
  const bf16* pa = A + (int64_t)(w * 16 + rl) * lda + qq * 8;
  const bf16* pb[4];
  pb[0] = Bm + (int64_t)rl * ldb + qq * 8;
  pb[1] = pb[0] + (int64_t)16 * ldb;
  pb[2] = pb[0] + (int64_t)32 * ldb;
  pb[3] = pb[0] + (int64_t)48 * ldb;
  f32x4 acc[4] = {};
  bf16x8 av[2][U], bv[2][U][4];
#pragma unroll
  for (int u = 0; u < U; u++) {
    av[0][u] = *(const bf16x8*)(pa + u * 32);
#pragma unroll
    for (int j = 0; j < 4; j++)
      bv[0][u][j] = *(const bf16x8*)(pb[j] + u * 32);
  }
  constexpr int NI = KLEN / (32 * U);
#pragma unroll
  for (int it = 0; it < NI; it++) {
    const int cur = it & 1, nxt = cur ^ 1;
    if (it + 1 < NI) {
      int k = (it + 1) * 32 * U;
#pragma unroll
      for (int u = 0; u < U; u++) {
        av[nxt][u] = *(const bf16x8*)(pa + k + u * 32);
#pragma unroll
        for (int j = 0; j < 4; j++)
          bv[nxt][u][j] = *(const bf16x8*)(pb[j] + k + u * 32);
      }
    }
#pragma unroll
    for (int u = 0; u < U; u++)
#pragma unroll
      for (int j = 0; j < 4; j++)
        acc[j] = mfma16(av[cur][u], bv[cur][u][j], acc[j]);
  }
#pragma unroll
  for (int j = 0; j < 4; j++) {
    int gn = j * 16 + rl;
    float bb = bias ? bias[gn] : 0.0f;
#pragma unroll
    for (int r = 0; r < 4; r++) {
      int gm = w * 16 + qq * 4 + r;
      C[(int64_t)gm * ldc + gn] = (OutT)((acc[j][r] + bb) * scale);
    }
  }
}

// ------------------------------ prep (L1) ----------------------------------
// blocks: [0,7696) cvt (64B/thread), [7696,9744) W^T (k,v),
//         [9744,10512) bias-combine, [10512,10896) accum bias-init,
//         [10896,10960) O/l zero
struct CvtD { const float* src; bf16* dst; int end; };  // end: 16-float units
struct PrepArgs {
  CvtD d[10];
  const float *Wk, *Wv, *inw, *inb, *bq, *bk, *bv;
  const float *outb, *gb1, *gb2, *ib1, *ib2;
  bf16* WT;
  float *bc, *msR, *g1R, *gateR, *h1R, *out, *Oraw, *lmat;
};

__global__ __launch_bounds__(256) void prep_kernel(PrepArgs a) {
  const int bx = blockIdx.x, tid = threadIdx.x;
  if (bx < 7696) {
    int g = bx * 256 + tid;  // 16-float unit index
    CvtD dd = a.d[9];
    int begin = a.d[8].end;
#pragma unroll
    for (int t = 8; t >= 0; t--)
      if (g < a.d[t].end) { dd = a.d[t]; begin = t ? a.d[t - 1].end : 0; }
    int i = (g - begin) * 16;
#pragma unroll
    for (int u = 0; u < 4; u++) {
      float4 v = *(const float4*)(dd.src + i + u * 4);
      bf16x4 o = { (bf16)v.x, (bf16)v.y, (bf16)v.z, (bf16)v.w };
      *(bf16x4*)(dd.dst + i + u * 4) = o;
    }
  } else if (bx < 9744) {
    int t = bx - 7696;
    int z = t >> 10, rem = t & 1023;   // z: 0 -> Wk, 1 -> Wv
    const float* src = z == 0 ? a.Wk : a.Wv;
    bf16* out = a.WT + (int64_t)(z + 1) * D_ * D_;
    __shared__ bf16 tile[32][33];
    int tx = tid & 31, ty = tid >> 5;
    int r0 = (rem >> 5) * 32, c0 = (rem & 31) * 32;
#pragma unroll
    for (int i = 0; i < 32; i += 8)
      tile[ty + i][tx] = (bf16)src[(int64_t)(r0 + ty + i) * D_ + c0 + tx];
    __syncthreads();
#pragma unroll
    for (int i = 0; i < 32; i += 8)
      out[(int64_t)(c0 + ty + i) * D_ + r0 + tx] = tile[tx][ty + i];
  } else if (bx < 10512) {
    int t = bx - 9744;
    int w = tid >> 6, lane = tid & 63;
    int ng = t * 4 + w;  // [0, 3072)
    int z = ng >> 10;
    const float* Wi = a.inw + (int64_t)ng * D_;
    const float* b = z == 0 ? a.bq : z == 1 ? a.bk : a.bv;
    float acc = 0.f;
#pragma unroll
    for (int l = 0; l < D_; l += 64) acc += Wi[l + lane] * b[l + lane];
#pragma unroll
    for (int m = 32; m; m >>= 1) acc += __shfl_xor(acc, m, 64);
    if (lane == 0) a.bc[ng] = acc + a.inb[ng];
  } else if (bx < 10896) {
    int t = bx - 10512;           // [0, 384)
    int seg = t >> 6, row = t & 63;
    int n = tid * 4;              // [0, 1024)
    const float* b;
    float* dst;
    int bn = n;
    if (seg == 0)      { dst = a.msR   + row * 1024;        b = a.outb; }
    else if (seg == 1) { dst = a.g1R   + row * 1024;        b = a.gb1;  }
    else if (seg == 2) { dst = a.gateR + row * 1024;        b = a.gb2;  }
    else if (seg == 3) { dst = a.h1R   + row * 2048;        b = a.ib1;  }
    else if (seg == 4) { dst = a.h1R   + row * 2048 + 1024; b = a.ib1; bn = 1024 + n; }
    else               { dst = a.out   + row * 1024;        b = a.ib2;  }
    *(float4*)(dst + n) = *(const float4*)(b + bn);
  } else {
    int b = bx - 10896;           // [0, 64): O/l zero
    float4 z4 = {0.f, 0.f, 0.f, 0.f};
    *(float4*)(a.Oraw + b * 1024 + tid * 4) = z4;
    if (b < 16 && tid < 64) a.lmat[b * 64 + tid] = 0.f;
  }
}

// --------------- L2: split-K x4 Wc partials (k,v) + thin q1 ----------------
// grid 528: [0,512) big blocks: 128^2 tile, K=256 chunk, fp32 partial store;
//           [512,528) thin: q1 = x @ Wq^T (no bias, scale 1).
// bid decode: n0=(bid&7)*128, m0=((bid>>3)&7)*128, zc=bid>>6 in [0,8):
//   z=zc>>2 (0=k,1=v), kc=zc&3 (K chunk). Partials Wcp[zc][1024][1024] fp32.
__global__ __launch_bounds__(256) void gemm_l2(
    const bf16* __restrict__ inpj,  // [3D][D]; rows D..3D = Wik,Wiv
    const bf16* __restrict__ WT,    // slots 1,2 = Wk^T, Wv^T (bf16)
    float* __restrict__ Wcp,        // [8][D][D] partials (aliases kh/vhT)
    const bf16* __restrict__ xbf, const bf16* __restrict__ Wqb,
    bf16* __restrict__ q1) {
  const int bid = blockIdx.x;
  if (bid >= 512) {
    int n0q = (bid - 512) * 64;
    thin_gemm<2, 1024, bf16>(xbf, D_, Wqb + (int64_t)n0q * D_, D_,
                             q1 + n0q, D_, nullptr, 1.0f);
    return;
  }
  const int n0 = (bid & 7) * 128;
  const int m0 = ((bid >> 3) & 7) * 128;
  const int zc = bid >> 6;
  const int z = zc >> 2, kc = zc & 3;
  const bf16* A = inpj + (int64_t)(z + 1) * D_ * D_ + kc * 256;
  const bf16* Bm = WT + (int64_t)(z + 1) * D_ * D_ + kc * 256;
  float* C = Wcp + (int64_t)zc * D_ * D_;

  __shared__ alignas(16) bf16 As[128 * 32];
  __shared__ alignas(16) bf16 Bs[128 * 32];
  const int tid = threadIdx.x, lane = tid & 63, w = tid >> 6;
  const int wm = (w & 1) * 64, wn = (w >> 1) * 64;
  const int rl = lane & 15, qq = lane >> 4;
  f32x4 acc[4][4] = {};

  int c0 = w * 64 + lane, c1 = (4 + w) * 64 + lane;
  int ra0 = c0 >> 2, qa0 = (c0 & 3) ^ ((ra0 >> 1) & 3);
  int ra1 = c1 >> 2, qa1 = (c1 & 3) ^ ((ra1 >> 1) & 3);
  const bf16* gA0 = A + (int64_t)(m0 + ra0) * D_ + qa0 * 8;
  const bf16* gA1 = A + (int64_t)(m0 + ra1) * D_ + qa1 * 8;
  const bf16* gB0 = Bm + (int64_t)(n0 + ra0) * D_ + qa0 * 8;
  const bf16* gB1 = Bm + (int64_t)(n0 + ra1) * D_ + qa1 * 8;
  bf16* lA0 = As + w * 512;
  bf16* lA1 = As + (4 + w) * 512;
  bf16* lB0 = Bs + w * 512;
  bf16* lB1 = Bs + (4 + w) * 512;

  for (int k0 = 0; k0 < 256; k0 += 32) {
    __syncthreads();
    gload16(gA0 + k0, lA0);
    gload16(gA1 + k0, lA1);
    gload16(gB0 + k0, lB0);
    gload16(gB1 + k0, lB1);
    __syncthreads();
    bf16x8 af[4], bb[4];
#pragma unroll
    for (int i = 0; i < 4; i++) {
      int r = wm + i * 16 + rl;
      af[i] = *(const bf16x8*)(As + r * 32 + (qq ^ ((r >> 1) & 3)) * 8);
    }
#pragma unroll
    for (int j = 0; j < 4; j++) {
      int r = wn + j * 16 + rl;
      bb[j] = *(const bf16x8*)(Bs + r * 32 + (qq ^ ((r >> 1) & 3)) * 8);
    }
#pragma unroll
    for (int i = 0; i < 4; i++)
#pragma unroll
      for (int j = 0; j < 4; j++)
        acc[i][j] = mfma16(af[i], bb[j], acc[i][j]);
  }
#pragma unroll
  for (int j = 0; j < 4; j++) {
    int gn = n0 + wn + j * 16 + rl;
#pragma unroll
    for (int i = 0; i < 4; i++) {
      int gm0 = m0 + wm + i * 16 + qq * 4;
#pragma unroll
      for (int r = 0; r < 4; r++)
        C[(int64_t)(gm0 + r) * D_ + gn] = acc[i][j][r];
    }
  }
}

// --------------- L3: sum 4 partials -> bf16 Wc (slots 1,2) -----------------
__global__ __launch_bounds__(256) void cvt_wc(
    const float* __restrict__ Wcp, bf16* __restrict__ Wc) {
  const int z = blockIdx.x >> 10, b = blockIdx.x & 1023;
  const int i = (b * 256 + threadIdx.x) * 4;
  const float* p = Wcp + (int64_t)(z * 4) * D_ * D_ + i;
  float4 s = *(const float4*)p;
#pragma unroll
  for (int kc = 1; kc < 4; kc++) {
    float4 t = *(const float4*)(p + (int64_t)kc * D_ * D_);
    s.x += t.x; s.y += t.y; s.z += t.z; s.w += t.w;
  }
  bf16x4 o = { (bf16)s.x, (bf16)s.y, (bf16)s.z, (bf16)s.w };
  *(bf16x4*)(Wc + (int64_t)(z + 1) * D_ * D_ + i) = o;
}

// ----------------- L4: 256^2-tile phase-split GEMM (kh + vhT) --------------
__global__ __launch_bounds__(512) void gemm256(
    const bf16* __restrict__ A,    // mkmv (z=0: mk, z=1: mv)
    const bf16* __restrict__ Wc,   // +D*D = Wc_k, +2D*D = Wc_v
    const float* __restrict__ bc,  // combined bias; +D = bik, +2D = biv
    bf16* __restrict__ kh, bf16* __restrict__ vhT,
    const bf16* __restrict__ qA, const bf16* __restrict__ qB,
    bf16* __restrict__ qC, const float* __restrict__ qbias) {
  extern __shared__ __align__(16) bf16 lds[];  // 4 * (8192 A + 8192 B) bf16
  const int bid = blockIdx.x;
  if (bid >= 256) {  // thin qh blocks at grid tail: qh = q1 @ Wiq^T + bc_q
    if (threadIdx.x < 256) {
      int n0q = (bid - 256) * 64;
      thin_gemm<2, 1024, bf16>(qA, D_, qB + (int64_t)n0q * D_, D_,
                               qC + n0q, D_, qbias + n0q, 0.125f);
    }
    return;
  }
  const int lin = bid;
  const int xcd = lin & 7, s = lin >> 3;
  const int z = xcd >> 2;
  const int m0 = ((xcd & 3) * 8 + (s >> 2)) * 256;
  const int n0 = (s & 3) * 256;
  const bf16* Ab = A + (int64_t)z * M_ * D_;
  const bf16* Bb = Wc + (int64_t)(z + 1) * D_ * D_;
  const float* bias = bc + (z + 1) * D_;

  const int tid = threadIdx.x, lane = tid & 63, w = tid >> 6;
  const int rl = lane & 15, qq = lane >> 4;
  const int wr = w >> 2, wcn = w & 3;

  const int ci0 = w * 128 + lane, ci1 = ci0 + 64;
  const int ra0 = ci0 >> 2, ca0 = (ci0 & 3) ^ ((ra0 >> 1) & 3);
  const int ra1 = ci1 >> 2, ca1 = (ci1 & 3) ^ ((ra1 >> 1) & 3);
  const bf16* gA0 = Ab + (int64_t)(m0 + ra0) * D_ + ca0 * 8;
  const bf16* gA1 = Ab + (int64_t)(m0 + ra1) * D_ + ca1 * 8;
  const bf16* gB0 = Bb + (int64_t)(n0 + ra0) * D_ + ca0 * 8;
  const bf16* gB1 = Bb + (int64_t)(n0 + ra1) * D_ + ca1 * 8;
  const int lA0 = w * 1024, lA1 = lA0 + 512;

  f32x4 acc[8][4] = {};
  bf16x8 bfr[4], afr[4];
  const int sq8 = (qq ^ ((rl >> 1) & 3)) * 8;

#define SCB __builtin_amdgcn_sched_barrier(0)
#define BARR __builtin_amdgcn_s_barrier()
#define VMW(N) asm volatile("s_waitcnt vmcnt(" #N ")")

#define STAGE_FULL(BUF, KT)                          \
  do {                                               \
    bf16* bse_ = lds + (BUF) * 16384;                \
    gload16(gA0 + (KT) * 32, bse_ + lA0);            \
    gload16(gA1 + (KT) * 32, bse_ + lA1);            \
    gload16(gB0 + (KT) * 32, bse_ + 8192 + lA0);     \
    gload16(gB1 + (KT) * 32, bse_ + 8192 + lA1);     \
  } while (0)

#define PH_A(BUF, DOSTAGE, SKT)                                              \
  do {                                                                       \
    const bf16* ba_ = lds + (BUF) * 16384;                                   \
    const bf16* bb_ = ba_ + 8192;                                            \
    for (int j = 0; j < 4; j++)                                              \
      bfr[j] = *(const bf16x8*)(bb_ + (wcn * 64 + j * 16 + rl) * 32 + sq8);  \
    for (int mi = 0; mi < 4; mi++)                                           \
      afr[mi] = *(const bf16x8*)(ba_ + (wr * 128 + mi * 16 + rl) * 32 + sq8);\
    if (DOSTAGE) {                                                           \
      bf16* bse_ = lds + ((SKT) & 3) * 16384;                                \
      gload16(gA0 + (SKT) * 32, bse_ + lA0);                                 \
      gload16(gA1 + (SKT) * 32, bse_ + lA1);                                 \
    }                                                                        \
    SCB; BARR; SCB;                                                          \
    __builtin_amdgcn_s_setprio(1);                                           \
    for (int mi = 0; mi < 4; mi++)                                           \
      for (int j = 0; j < 4; j++)                                            \
        acc[mi][j] = mfma16(afr[mi], bfr[j], acc[mi][j]);                    \
    __builtin_amdgcn_s_setprio(0);                                           \
    SCB; BARR; SCB;                                                          \
  } while (0)

#define PH_B(BUF, DOSTAGE, SKT, VMSTMT)                                      \
  do {                                                                       \
    const bf16* ba_ = lds + (BUF) * 16384;                                   \
    for (int mi = 0; mi < 4; mi++)                                           \
      afr[mi] =                                                              \
          *(const bf16x8*)(ba_ + (wr * 128 + (mi + 4) * 16 + rl) * 32 + sq8);\
    if (DOSTAGE) {                                                           \
      bf16* bse_ = lds + ((SKT) & 3) * 16384;                                \
      gload16(gB0 + (SKT) * 32, bse_ + 8192 + lA0);                          \
      gload16(gB1 + (SKT) * 32, bse_ + 8192 + lA1);                          \
    }                                                                        \
    VMSTMT;                                                                  \
    SCB; BARR; SCB;                                                          \
    __builtin_amdgcn_s_setprio(1);                                           \
    for (int mi = 0; mi < 4; mi++)                                           \
      for (int j = 0; j < 4; j++)                                            \
        acc[mi + 4][j] = mfma16(afr[mi], bfr[j], acc[mi + 4][j]);            \
    __builtin_amdgcn_s_setprio(0);                                           \
    SCB; BARR; SCB;                                                          \
  } while (0)

  STAGE_FULL(0, 0);
  STAGE_FULL(1, 1);
  STAGE_FULL(2, 2);
  VMW(8);
  SCB; BARR; SCB;

#pragma unroll 1
  for (int t = 0; t < 7; t++) {
    const int kb = t * 4;
    PH_A(0, 1, kb + 3); PH_B(0, 1, kb + 3, VMW(8));
    PH_A(1, 1, kb + 4); PH_B(1, 1, kb + 4, VMW(8));
    PH_A(2, 1, kb + 5); PH_B(2, 1, kb + 5, VMW(8));
    PH_A(3, 1, kb + 6); PH_B(3, 1, kb + 6, VMW(8));
  }
  PH_A(0, 1, 31); PH_B(0, 1, 31, VMW(8));
  PH_A(1, 0, 0);  PH_B(1, 0, 0, VMW(4));
  PH_A(2, 0, 0);  PH_B(2, 0, 0, VMW(0));
  PH_A(3, 0, 0);  PH_B(3, 0, 0, (void)0);

#undef SCB
#undef BARR
#undef VMW
#undef STAGE_FULL
#undef PH_A
#undef PH_B

  if (z == 0) {
#pragma unroll
    for (int j = 0; j < 4; j++) {
      int gn = n0 + wcn * 64 + j * 16 + rl;
      float bb2 = bias[gn];
#pragma unroll
      for (int mi = 0; mi < 8; mi++) {
        int gm0 = m0 + wr * 128 + mi * 16 + qq * 4;
#pragma unroll
        for (int r = 0; r < 4; r++)
          kh[(int64_t)(gm0 + r) * D_ + gn] = (bf16)(acc[mi][j][r] + bb2);
      }
    }
  } else {
#pragma unroll
    for (int j = 0; j < 4; j++) {
      int gn = n0 + wcn * 64 + j * 16 + rl;
      float bb2 = bias[gn];
#pragma unroll
      for (int mi = 0; mi < 8; mi++) {
        int gm0 = m0 + wr * 128 + mi * 16 + qq * 4;
        f32x4 a = acc[mi][j];
        bf16x4 o = { (bf16)(a[0] + bb2), (bf16)(a[1] + bb2),
                     (bf16)(a[2] + bb2), (bf16)(a[3] + bb2) };
        *(bf16x4*)(vhT + (int64_t)gn * M_ + gm0) = o;
      }
    }
  }
}

// --------------------------- flash, no-max (L5) ----------------------------
__global__ __launch_bounds__(256, 2) void flash_kernel(
    const bf16* __restrict__ qh, const bf16* __restrict__ kh,
    const bf16* __restrict__ vhT, float* __restrict__ Oraw,
    float* __restrict__ lmat) {
  const int tid = threadIdx.x, lane = tid & 63, w = tid >> 6;
  const int rl = lane & 15, qq = lane >> 4;
  const int h = blockIdx.x >> 4, c = blockIdx.x & 15;
  __shared__ alignas(16) bf16 Plds[4 * 16 * 72];
  const bf16* qhp = qh + (int64_t)(w * 16 + rl) * D_ + h * 64 + qq * 8;
  bf16x8 aq0 = *(const bf16x8*)(qhp);
  bf16x8 aq1 = *(const bf16x8*)(qhp + 32);
  float lsum[4] = {0.f, 0.f, 0.f, 0.f};
  f32x4 acc_o[4] = {};
  bf16* pl = Plds + w * 1152;
  const bf16* khb = kh + (int64_t)(c * 512) * D_ + h * 64 + qq * 8;
  const bf16* vtb = vhT + (int64_t)(h * 64) * M_ + c * 512 + qq * 8;
  for (int nt = 0; nt < 8; nt++) {
    int mb = nt * 64;
    bf16x8 bk0[4], bk1[4], vv0[4], vv1[4];
#pragma unroll
    for (int j = 0; j < 4; j++) {
      const bf16* p = khb + (int64_t)(mb + j * 16 + rl) * D_;
      bk0[j] = *(const bf16x8*)(p);
      bk1[j] = *(const bf16x8*)(p + 32);
      const bf16* q = vtb + (int64_t)(j * 16 + rl) * M_ + mb;
      vv0[j] = *(const bf16x8*)(q);
      vv1[j] = *(const bf16x8*)(q + 32);
    }
    f32x4 s[4] = {};
#pragma unroll
    for (int j = 0; j < 4; j++) {
      s[j] = mfma16(aq0, bk0[j], s[j]);
      s[j] = mfma16(aq1, bk1[j], s[j]);
    }
#pragma unroll
    for (int j = 0; j < 4; j++)
#pragma unroll
      for (int r = 0; r < 4; r++) {
        float p = __expf(s[j][r]);
        lsum[r] += p;
        pl[(qq * 4 + r) * 72 + j * 16 + rl] = (bf16)p;
      }
    bf16x8 pa0 = *(const bf16x8*)(pl + rl * 72 + qq * 8);
    bf16x8 pa1 = *(const bf16x8*)(pl + rl * 72 + 32 + qq * 8);
#pragma unroll
    for (int j = 0; j < 4; j++) {
      acc_o[j] = mfma16(pa0, vv0[j], acc_o[j]);
      acc_o[j] = mfma16(pa1, vv1[j], acc_o[j]);
    }
  }
#pragma unroll
  for (int msk = 1; msk <= 8; msk <<= 1)
#pragma unroll
    for (int r = 0; r < 4; r++) lsum[r] += __shfl_xor(lsum[r], msk, 64);
#pragma unroll
  for (int j = 0; j < 4; j++)
#pragma unroll
    for (int r = 0; r < 4; r++)
      atomicAdd(&Oraw[(int64_t)(w * 16 + qq * 4 + r) * D_ + h * 64 + j * 16 + rl],
                acc_o[j][r]);
  if (rl == 0)
#pragma unroll
    for (int r = 0; r < 4; r++)
      atomicAdd(&lmat[h * 64 + w * 16 + qq * 4 + r], lsum[r]);
}

// ----------------------- split-K atomic tail stage -------------------------
// Craw[m][n0..n0+64) += A_chunk(m, NKK*32) @ Bw_chunk^T, via atomicAdd.
// KIND: 0=bf16; 1=fp32; 2=relu(fp32); 3=sigmoid(p0)*p1; 4=p0*(1/l[h][m]).
struct Chunk { const void* p0; const void* p1; int ld; int kind; };
struct StageArgs { Chunk c[16]; };

template <int NKK>
__global__ __launch_bounds__(256) void tail_stage(
    StageArgs sa, const bf16* __restrict__ Bw, int ldb,
    float* __restrict__ Craw, int ldc) {
  const int n0 = blockIdx.x * 64, kc = blockIdx.y;
  const int bk0 = kc * NKK * 32;
  const Chunk ch = sa.c[kc];
  const int tid = threadIdx.x, lane = tid & 63, w = tid >> 6;
  const int rl = lane & 15, qq = lane >> 4;
  const int m = w * 16 + rl;
  const bf16* pb[4];
#pragma unroll
  for (int j = 0; j < 4; j++)
    pb[j] = Bw + (int64_t)(n0 + j * 16 + rl) * ldb + bk0 + qq * 8;
  f32x4 acc[4] = {};
#pragma unroll
  for (int kk = 0; kk < NKK; kk++) {
    bf16x8 af;
    if (ch.kind == 0) {
      af = *(const bf16x8*)((const bf16*)ch.p0 + (int64_t)m * ch.ld +
                            kk * 32 + qq * 8);
    } else {
      const float* p = (const float*)ch.p0 + (int64_t)m * ch.ld + kk * 32 + qq * 8;
      float4 u0 = *(const float4*)p;
      float4 u1 = *(const float4*)(p + 4);
      if (ch.kind == 2) {
        u0.x = fmaxf(u0.x, 0.f); u0.y = fmaxf(u0.y, 0.f);
        u0.z = fmaxf(u0.z, 0.f); u0.w = fmaxf(u0.w, 0.f);
        u1.x = fmaxf(u1.x, 0.f); u1.y = fmaxf(u1.y, 0.f);
        u1.z = fmaxf(u1.z, 0.f); u1.w = fmaxf(u1.w, 0.f);
      } else if (ch.kind == 3) {
        const float* pm = (const float*)ch.p1 + (int64_t)m * ch.ld + kk * 32 + qq * 8;
        float4 m0 = *(const float4*)pm;
        float4 m1 = *(const float4*)(pm + 4);
        u0.x = m0.x / (1.f + __expf(-u0.x)); u0.y = m0.y / (1.f + __expf(-u0.y));
        u0.z = m0.z / (1.f + __expf(-u0.z)); u0.w = m0.w / (1.f + __expf(-u0.w));
        u1.x = m1.x / (1.f + __expf(-u1.x)); u1.y = m1.y / (1.f + __expf(-u1.y));
        u1.z = m1.z / (1.f + __expf(-u1.z)); u1.w = m1.w / (1.f + __expf(-u1.w));
      } else if (ch.kind == 4) {
        int hidx = (bk0 + kk * 32) >> 6;
        float linv = 1.0f / ((const float*)ch.p1)[hidx * 64 + m];
        u0.x *= linv; u0.y *= linv; u0.z *= linv; u0.w *= linv;
        u1.x *= linv; u1.y *= linv; u1.z *= linv; u1.w *= linv;
      }
      af = (bf16x8){ (bf16)u0.x, (bf16)u0.y, (bf16)u0.z, (bf16)u0.w,
                     (bf16)u1.x, (bf16)u1.y, (bf16)u1.z, (bf16)u1.w };
    }
    bf16x8 bf_[4];
#pragma unroll
    for (int j = 0; j < 4; j++) bf_[j] = *(const bf16x8*)(pb[j] + kk * 32);
#pragma unroll
    for (int j = 0; j < 4; j++) acc[j] = mfma16(af, bf_[j], acc[j]);
  }
#pragma unroll
  for (int j = 0; j < 4; j++) {
    int gn = n0 + j * 16 + rl;
#pragma unroll
    for (int r = 0; r < 4; r++) {
      int gm = w * 16 + qq * 4 + r;
      atomicAdd(&Craw[(int64_t)gm * ldc + gn], acc[j][r]);
    }
  }
}

// ------------------------------- launch ------------------------------------
extern "C" void kernel_launch(void* const* d_in, const int* in_sizes, int n_in,
                              void* d_out, int out_size, void* d_ws,
                              size_t ws_size, hipStream_t stream) {
  (void)in_sizes; (void)n_in; (void)out_size;
  const float* x    = (const float*)d_in[0];
  const float* mk   = (const float*)d_in[1];
  const float* mv   = (const float*)d_in[2];
  const float* Wq   = (const float*)d_in[3];
  const float* bq   = (const float*)d_in[4];
  const float* Wk   = (const float*)d_in[5];
  const float* bk   = (const float*)d_in[6];
  const float* Wv   = (const float*)d_in[7];
  const float* bv   = (const float*)d_in[8];
  const float* inw  = (const float*)d_in[9];
  const float* inb  = (const float*)d_in[10];
  const float* outw = (const float*)d_in[11];
  const float* outb = (const float*)d_in[12];
  const float* gW1  = (const float*)d_in[13];
  const float* gb1  = (const float*)d_in[14];
  const float* gW2  = (const float*)d_in[15];
  const float* gb2  = (const float*)d_in[16];
  const float* iW1  = (const float*)d_in[17];
  const float* ib1  = (const float*)d_in[18];
  const float* iW2  = (const float*)d_in[19];
  const float* ib2  = (const float*)d_in[20];

  char* ws = (char*)d_ws;
  size_t off = 0;
  auto alloc = [&](size_t bytes) {
    char* p = ws + off;
    off += (bytes + 255) & ~(size_t)255;
    return p;
  };
  bf16* mkmv  = (bf16*)alloc((size_t)2 * M_ * D_ * 2);
  bf16* inpj  = (bf16*)alloc((size_t)3 * D_ * D_ * 2);
  bf16* WT    = (bf16*)alloc((size_t)3 * D_ * D_ * 2);
  bf16* Wc    = (bf16*)alloc((size_t)3 * D_ * D_ * 2);
  float* bc   = (float*)alloc(3 * D_ * 4);
  bf16* xbf   = (bf16*)alloc((size_t)B_ * D_ * 2);
  bf16* qh    = (bf16*)alloc((size_t)B_ * D_ * 2);
  bf16* kh    = (bf16*)alloc((size_t)M_ * D_ * 2);   // also Wcp partials
  bf16* vhT   = (bf16*)alloc((size_t)M_ * D_ * 2);   // (contiguous with kh)
  float* Oraw = (float*)alloc((size_t)B_ * D_ * 4);
  float* lmat = (float*)alloc((size_t)H_ * B_ * 4);
  float* msR  = (float*)alloc((size_t)B_ * D_ * 4);
  float* g1R  = (float*)alloc((size_t)B_ * D_ * 4);
  float* gateR= (float*)alloc((size_t)B_ * D_ * 4);
  float* h1R  = (float*)alloc((size_t)B_ * 2 * D_ * 4);
  bf16* gW1b  = (bf16*)alloc((size_t)D_ * 2 * D_ * 2);
  bf16* gW2b  = (bf16*)alloc((size_t)D_ * D_ * 2);
  bf16* iW1b  = (bf16*)alloc((size_t)2 * D_ * 2 * D_ * 2);
  bf16* iW2b  = (bf16*)alloc((size_t)D_ * 2 * D_ * 2);
  bf16* outwb = (bf16*)alloc((size_t)D_ * D_ * 2);
  bf16* Wqb   = (bf16*)alloc((size_t)D_ * D_ * 2);
  bf16* q1    = (bf16*)alloc((size_t)B_ * D_ * 2);
  if (ws_size < off) return;
  // Wc split-K partials alias kh+vhT (8 * 4MB == 32MB == kh+vhT exactly);
  // overwritten by gemm256 only after cvt_wc has consumed them.
  float* Wcp = (float*)kh;

  // L1: prep  (cvt ends in 16-float units)
  PrepArgs pa;
  pa.d[0] = { mk,   mkmv,           524288 };
  pa.d[1] = { mv,   mkmv + M_ * D_, 1048576 };
  pa.d[2] = { inw,  inpj,           1245184 };
  pa.d[3] = { gW1,  gW1b,           1376256 };
  pa.d[4] = { gW2,  gW2b,           1441792 };
  pa.d[5] = { iW1,  iW1b,           1703936 };
  pa.d[6] = { iW2,  iW2b,           1835008 };
  pa.d[7] = { outw, outwb,          1900544 };
  pa.d[8] = { Wq,   Wqb,            1966080 };
  pa.d[9] = { x,    xbf,            1970176 };
  pa.Wk = Wk; pa.Wv = Wv; pa.inw = inw; pa.inb = inb;
  pa.bq = bq; pa.bk = bk; pa.bv = bv;
  pa.outb = outb; pa.gb1 = gb1; pa.gb2 = gb2; pa.ib1 = ib1; pa.ib2 = ib2;
  pa.WT = WT; pa.bc = bc; pa.msR = msR; pa.g1R = g1R; pa.gateR = gateR;
  pa.h1R = h1R; pa.out = (float*)d_out; pa.Oraw = Oraw; pa.lmat = lmat;
  prep_kernel<<<dim3(10960), 256, 0, stream>>>(pa);

  // L2: Wc partials (split-K x4, 2/CU) + thin q1 = x @ Wq^T
  gemm_l2<<<dim3(528), 256, 0, stream>>>(inpj, WT, Wcp, xbf, Wqb, q1);

  // L3: sum partials -> bf16 Wc slots 1,2
  cvt_wc<<<dim3(2048), 256, 0, stream>>>(Wcp, Wc);

  // L4: kh / vhT via phase-split 256^2 kernel (+ qh thin blocks at tail)
  hipFuncSetAttribute((const void*)gemm256,
                      hipFuncAttributeMaxDynamicSharedMemorySize, 131072);
  gemm256<<<dim3(272), dim3(512), 131072, stream>>>(
      mkmv, Wc, bc, kh, vhT, q1, inpj, qh, bc);

  // L5: flash partials -> atomic Oraw / lmat
  flash_kernel<<<dim3(256), 256, 0, stream>>>(qh, kh, vhT, Oraw, lmat);

  // L6 S1: msR += (Oraw/l) @ outwb^T   grid (16 n, 8 kc of 128)
  StageArgs s1;
  for (int kc = 0; kc < 8; kc++) s1.c[kc] = { Oraw + kc * 128, lmat, D_, 4 };
  tail_stage<4><<<dim3(16, 8), 256, 0, stream>>>(s1, outwb, D_, msR, D_);

  // L7 S2: g1R += [x | msR] @ gW1^T    grid (16, 16 kc of 128, K=2048)
  StageArgs s2;
  for (int kc = 0; kc < 8; kc++)  s2.c[kc] = { xbf + kc * 128, nullptr, D_, 0 };
  for (int kc = 8; kc < 16; kc++) s2.c[kc] = { msR + (kc - 8) * 128, nullptr, D_, 1 };
  tail_stage<4><<<dim3(16, 16), 256, 0, stream>>>(s2, gW1b, 2 * D_, g1R, D_);

  // L8 S3: gateR += relu(g1R) @ gW2^T  grid (16, 8)
  StageArgs s3;
  for (int kc = 0; kc < 8; kc++) s3.c[kc] = { g1R + kc * 128, nullptr, D_, 2 };
  tail_stage<4><<<dim3(16, 8), 256, 0, stream>>>(s3, gW2b, D_, gateR, D_);

  // L9 S4: h1R += [x | sig(gateR)*msR] @ iW1^T  grid (32, 16)
  StageArgs s4;
  for (int kc = 0; kc < 8; kc++)  s4.c[kc] = { xbf + kc * 128, nullptr, D_, 0 };
  for (int kc = 8; kc < 16; kc++)
    s4.c[kc] = { gateR + (kc - 8) * 128, msR + (kc - 8) * 128, D_, 3 };
  tail_stage<4><<<dim3(32, 16), 256, 0, stream>>>(s4, iW1b, 2 * D_, h1R, 2 * D_);

  // L10 S5: out += relu(h1R) @ iW2^T   grid (16, 16, K=2048)
  StageArgs s5;
  for (int kc = 0; kc < 16; kc++) s5.c[kc] = { h1R + kc * 128, nullptr, 2 * D_, 2 };
  tail_stage<4><<<dim3(16, 16), 256, 0, stream>>>(s5, iW2b, 2 * D_,
                                                  (float*)d_out, D_);
}

// Round 6
// 351.011 us; speedup vs baseline: 1.5747x; 1.0256x over previous
//
#include <hip/hip_runtime.h>
#include <hip/hip_bf16.h>
#include <stdint.h>

// ---------------------------------------------------------------------------
// AstrocyteMemoryModule r13: 9 launches.
//  L1 prep r2: block-uniform segment decode, 128B/thread cvt (8 float4 in
//      flight) + W^T (q,k,v) + combined bias + accum bias-init + O/l zero
//  L2 Wc = Wi@W (batched 1024^3, BK=32, 128^2 structure)  [r9 revert]
//  L3 gemm_kv: 128x256 tiles, 512 blocks = 2/CU (TLP is the proven lever:
//      ~4900 cyc/K-step @1/CU vs ~1540 @4/CU), 4 waves, 3 LDS buffers
//      (72KB), depth-2 counted pipeline {vmcnt(6); bar; stage(kt+2);
//      compute(kt)} + 16 thin qh blocks at grid tail.
//  L4 flash (no-max exp; atomicAdd unnormalized O partials + row-sums l)
//  L5-L9 tail stages: split-K atomic GEMMs.
// ---------------------------------------------------------------------------

typedef __bf16 bf16;
typedef __bf16 bf16x4 __attribute__((ext_vector_type(4)));
typedef __bf16 bf16x8 __attribute__((ext_vector_type(8)));
typedef float f32x4 __attribute__((ext_vector_type(4)));

#define D_ 1024
#define M_ 8192
#define B_ 64
#define H_ 16

static __device__ __forceinline__ void gload16(const void* g, void* l) {
  __builtin_amdgcn_global_load_lds(
      (const __attribute__((address_space(1))) void*)g,
      (__attribute__((address_space(3))) void*)l, 16, 0, 0);
}

static __device__ __forceinline__ f32x4 mfma16(bf16x8 a, bf16x8 b, f32x4 c) {
  return __builtin_amdgcn_mfma_f32_16x16x32_bf16(a, b, c, 0, 0, 0);
}

// ---------------- thin GEMM (M=64): C = A @ B^T, reg-prefetched -------------
template <int U, int KLEN, typename OutT>
__device__ __forceinline__ void thin_gemm(
    const bf16* __restrict__ A, int lda,
    const bf16* __restrict__ Bm, int ldb,
    OutT* __restrict__ C, int ldc,
    const float* __restrict__ bias, float scale) {
  const int tid = threadIdx.x, lane = tid & 63, w = tid >> 6;
  const int rl = lane & 15, qq = lane >> 4;
  const bf16* pa = A + (int64_t)(w * 16 + rl) * lda + qq * 8;
  const bf16* pb[4];
  pb[0] = Bm + (int64_t)rl * ldb + qq * 8;
  pb[1] = pb[0] + (int64_t)16 * ldb;
  pb[2] = pb[0] + (int64_t)32 * ldb;
  pb[3] = pb[0] + (int64_t)48 * ldb;
  f32x4 acc[4] = {};
  bf16x8 av[2][U], bv[2][U][4];
#pragma unroll
  for (int u = 0; u < U; u++) {
    av[0][u] = *(const bf16x8*)(pa + u * 32);
#pragma unroll
    for (int j = 0; j < 4; j++)
      bv[0][u][j] = *(const bf16x8*)(pb[j] + u * 32);
  }
  constexpr int NI = KLEN / (32 * U);
#pragma unroll
  for (int it = 0; it < NI; it++) {
    const int cur = it & 1, nxt = cur ^ 1;
    if (it + 1 < NI) {
      int k = (it + 1) * 32 * U;
#pragma unroll
      for (int u = 0; u < U; u++) {
        av[nxt][u] = *(const bf16x8*)(pa + k + u * 32);
#pragma unroll
        for (int j = 0; j < 4; j++)
          bv[nxt][u][j] = *(const bf16x8*)(pb[j] + k + u * 32);
      }
    }
#pragma unroll
    for (int u = 0; u < U; u++)
#pragma unroll
      for (int j = 0; j < 4; j++)
        acc[j] = mfma16(av[cur][u], bv[cur][u][j], acc[j]);
  }
#pragma unroll
  for (int j = 0; j < 4; j++) {
    int gn = j * 16 + rl;
    float bb = bias ? bias[gn] : 0.0f;
#pragma unroll
    for (int r = 0; r < 4; r++) {
      int gm = w * 16 + qq * 4 + r;
      C[(int64_t)gm * ldc + gn] = (OutT)((acc[j][r] + bb) * scale);
    }
  }
}

// ------------------------------ prep (L1) ----------------------------------
// blocks: [0,3720) cvt (128B/thread, block-uniform segment),
//         [3720,6792) W^T (q,k,v), [6792,7560) bias-combine,
//         [7560,7944) accum bias-init, [7944,8008) O/l zero
// Every cvt region is a multiple of 8192 floats => a block never straddles
// segments => the descriptor search is wave-uniform (SALU).
struct CvtD { const float* src; bf16* dst; int end; };  // end in BLOCK units
struct PrepArgs {
  CvtD d[9];
  const float *Wq, *Wk, *Wv, *inw, *inb, *bq, *bk, *bv;
  const float *outb, *gb1, *gb2, *ib1, *ib2;
  bf16* WT;
  float *bc, *msR, *g1R, *gateR, *h1R, *out, *Oraw, *lmat;
};

__global__ __launch_bounds__(256) void prep_kernel(PrepArgs a) {
  const int bx = blockIdx.x, tid = threadIdx.x;
  if (bx < 3720) {
    CvtD dd = a.d[8];
    int begin = a.d[7].end;
#pragma unroll
    for (int t = 7; t >= 0; t--)
      if (bx < a.d[t].end) { dd = a.d[t]; begin = t ? a.d[t - 1].end : 0; }
    int64_t i = (int64_t)(bx - begin) * 8192 + tid * 32;
    const float* src = dd.src + i;
    bf16* dst = dd.dst + i;
    float4 v[8];
#pragma unroll
    for (int u = 0; u < 8; u++) v[u] = *(const float4*)(src + u * 4);
#pragma unroll
    for (int u = 0; u < 8; u++) {
      bf16x4 o = { (bf16)v[u].x, (bf16)v[u].y, (bf16)v[u].z, (bf16)v[u].w };
      *(bf16x4*)(dst + u * 4) = o;
    }
  } else if (bx < 6792) {
    int t = bx - 3720;
    int z = t >> 10, rem = t & 1023;   // z: 0=Wq 1=Wk 2=Wv
    const float* src = z == 0 ? a.Wq : z == 1 ? a.Wk : a.Wv;
    bf16* out = a.WT + (int64_t)z * D_ * D_;
    __shared__ bf16 tile[32][33];
    int tx = tid & 31, ty = tid >> 5;
    int r0 = (rem >> 5) * 32, c0 = (rem & 31) * 32;
#pragma unroll
    for (int i = 0; i < 32; i += 8)
      tile[ty + i][tx] = (bf16)src[(int64_t)(r0 + ty + i) * D_ + c0 + tx];
    __syncthreads();
#pragma unroll
    for (int i = 0; i < 32; i += 8)
      out[(int64_t)(c0 + ty + i) * D_ + r0 + tx] = tile[tx][ty + i];
  } else if (bx < 7560) {
    int t = bx - 6792;
    int w = tid >> 6, lane = tid & 63;
    int ng = t * 4 + w;  // [0, 3072)
    int z = ng >> 10;
    const float* Wi = a.inw + (int64_t)ng * D_;
    const float* b = z == 0 ? a.bq : z == 1 ? a.bk : a.bv;
    float acc = 0.f;
#pragma unroll
    for (int l = 0; l < D_; l += 64) acc += Wi[l + lane] * b[l + lane];
#pragma unroll
    for (int m = 32; m; m >>= 1) acc += __shfl_xor(acc, m, 64);
    if (lane == 0) a.bc[ng] = acc + a.inb[ng];
  } else if (bx < 7944) {
    int t = bx - 7560;            // [0, 384)
    int seg = t >> 6, row = t & 63;
    int n = tid * 4;              // [0, 1024)
    const float* b;
    float* dst;
    int bn = n;
    if (seg == 0)      { dst = a.msR   + row * 1024;        b = a.outb; }
    else if (seg == 1) { dst = a.g1R   + row * 1024;        b = a.gb1;  }
    else if (seg == 2) { dst = a.gateR + row * 1024;        b = a.gb2;  }
    else if (seg == 3) { dst = a.h1R   + row * 2048;        b = a.ib1;  }
    else if (seg == 4) { dst = a.h1R   + row * 2048 + 1024; b = a.ib1; bn = 1024 + n; }
    else               { dst = a.out   + row * 1024;        b = a.ib2;  }
    *(float4*)(dst + n) = *(const float4*)(b + bn);
  } else {
    int b = bx - 7944;            // [0, 64): O/l zero
    float4 z4 = {0.f, 0.f, 0.f, 0.f};
    *(float4*)(a.Oraw + b * 1024 + tid * 4) = z4;
    if (b < 16 && tid < 64) a.lmat[b * 64 + tid] = 0.f;
  }
}

// ------------------------- big GEMM: C = A @ B^T (BK=32) -------------------
// (L2 only: Wc_z = Wi_z @ W_z, grid (8,8,3))
__global__ __launch_bounds__(256) void gemm_big(
    const bf16* __restrict__ A, int lda, int64_t sA,
    const bf16* __restrict__ Bm, int ldb, int64_t sB,
    bf16* __restrict__ C, int ldc, int64_t sC, int K) {
  const int z = blockIdx.z, m0 = blockIdx.y * 128, n0 = blockIdx.x * 128;
  A += (int64_t)z * sA; Bm += (int64_t)z * sB;
  __shared__ alignas(16) bf16 As[128 * 32];
  __shared__ alignas(16) bf16 Bs[128 * 32];
  const int tid = threadIdx.x, lane = tid & 63, w = tid >> 6;
  const int wm = (w & 1) * 64, wn = (w >> 1) * 64;
  const int rl = lane & 15, qq = lane >> 4;
  f32x4 acc[4][4] = {};

  int c0 = w * 64 + lane, c1 = (4 + w) * 64 + lane;
  int ra0 = c0 >> 2, qa0 = (c0 & 3) ^ ((ra0 >> 1) & 3);
  int ra1 = c1 >> 2, qa1 = (c1 & 3) ^ ((ra1 >> 1) & 3);
  const bf16* gA0 = A + (int64_t)(m0 + ra0) * lda + qa0 * 8;
  const bf16* gA1 = A + (int64_t)(m0 + ra1) * lda + qa1 * 8;
  const bf16* gB0 = Bm + (int64_t)(n0 + ra0) * ldb + qa0 * 8;
  const bf16* gB1 = Bm + (int64_t)(n0 + ra1) * ldb + qa1 * 8;
  bf16* lA0 = As + w * 512;
  bf16* lA1 = As + (4 + w) * 512;
  bf16* lB0 = Bs + w * 512;
  bf16* lB1 = Bs + (4 + w) * 512;

  for (int k0 = 0; k0 < K; k0 += 32) {
    __syncthreads();
    gload16(gA0 + k0, lA0);
    gload16(gA1 + k0, lA1);
    gload16(gB0 + k0, lB0);
    gload16(gB1 + k0, lB1);
    __syncthreads();
    bf16x8 af[4], bb[4];
#pragma unroll
    for (int i = 0; i < 4; i++) {
      int r = wm + i * 16 + rl;
      af[i] = *(const bf16x8*)(As + r * 32 + (qq ^ ((r >> 1) & 3)) * 8);
    }
#pragma unroll
    for (int j = 0; j < 4; j++) {
      int r = wn + j * 16 + rl;
      bb[j] = *(const bf16x8*)(Bs + r * 32 + (qq ^ ((r >> 1) & 3)) * 8);
    }
#pragma unroll
    for (int i = 0; i < 4; i++)
#pragma unroll
      for (int j = 0; j < 4; j++)
        acc[i][j] = mfma16(af[i], bb[j], acc[i][j]);
  }
  C += (int64_t)z * sC;
#pragma unroll
  for (int j = 0; j < 4; j++) {
    int gn = n0 + wn + j * 16 + rl;
#pragma unroll
    for (int i = 0; i < 4; i++) {
      int gm0 = m0 + wm + i * 16 + qq * 4;
#pragma unroll
      for (int r = 0; r < 4; r++)
        C[(int64_t)(gm0 + r) * ldc + gn] = (bf16)acc[i][j][r];
    }
  }
}

// ----------------- L3: 128x256-tile GEMM, 2 blocks/CU (kh + vhT) -----------
// 512 main blocks (xcd-banded) + 16 thin qh blocks at tail. Block: 256 thr
// (4 waves, 1Mx4N: wave w owns cols w*64..), BK=32, 3 LDS buffers (24KB
// each, 72KB total => 2 blocks/CU). Depth-2 counted pipeline:
//   { vmcnt(6); barrier; stage(kt+2); compute(kt) }   [6 gloads per stage]
// vmcnt(6): outstanding = stages {kt,kt+1} = 12; <=6 left => kt retired.
// Single barrier also protects buf[(kt+2)%3] overwrite: all waves finished
// compute(kt-1)'s ds_reads (results consumed by MFMAs before the barrier).
__global__ __launch_bounds__(256) void gemm_kv(
    const bf16* __restrict__ A,    // mkmv (z=0: mk, z=1: mv)
    const bf16* __restrict__ Wc,   // +D*D = Wc_k, +2D*D = Wc_v
    const float* __restrict__ bc,  // combined bias; +D = bik, +2D = biv
    bf16* __restrict__ kh, bf16* __restrict__ vhT,
    const bf16* __restrict__ qA, const bf16* __restrict__ qB,
    bf16* __restrict__ qC, const float* __restrict__ qbias) {
  extern __shared__ __align__(16) bf16 lds[];  // 3 * 12288 bf16 = 72 KB
  const int bid = blockIdx.x;
  if (bid >= 512) {  // thin qh: qh = (xbf @ Wc_q^T + bc_q) * 0.125
    int n0q = (bid - 512) * 64;
    thin_gemm<2, 1024, bf16>(qA, D_, qB + (int64_t)n0q * D_, D_,
                             qC + n0q, D_, qbias + n0q, 0.125f);
    return;
  }
  const int xcd = bid & 7, s = bid >> 3;             // s in [0,64)
  const int z = xcd >> 2;                            // 0: kh, 1: vhT
  const int m0 = ((xcd & 3) * 16 + (s >> 2)) * 128;  // [0,8192)
  const int n0 = (s & 3) * 256;                      // [0,1024)
  const bf16* Ab = A + (int64_t)z * M_ * D_;
  const bf16* Bb = Wc + (int64_t)(z + 1) * D_ * D_;
  const float* bias = bc + (z + 1) * D_;

  const int tid = threadIdx.x, lane = tid & 63, w = tid >> 6;
  const int rl = lane & 15, qq = lane >> 4;

  // staging: A = 512 chunks (2/thread), B = 1024 chunks (4/thread); linear
  // LDS dest, pre-swizzled global source (chunk c = (ci&3)^((row>>1)&3)).
  const bf16* gA0_; const bf16* gA1_;
  const bf16* gB_[4];
  {
    int ci0 = w * 64 + lane, ci1 = ci0 + 256;
    int r0 = ci0 >> 2, c0 = (ci0 & 3) ^ ((r0 >> 1) & 3);
    int r1 = ci1 >> 2, c1 = (ci1 & 3) ^ ((r1 >> 1) & 3);
    gA0_ = Ab + (int64_t)(m0 + r0) * D_ + c0 * 8;
    gA1_ = Ab + (int64_t)(m0 + r1) * D_ + c1 * 8;
#pragma unroll
    for (int s2 = 0; s2 < 4; s2++) {
      int ci = w * 64 + lane + s2 * 256;
      int rb = ci >> 2, cb = (ci & 3) ^ ((rb >> 1) & 3);
      gB_[s2] = Bb + (int64_t)(n0 + rb) * D_ + cb * 8;
    }
  }
  const int lA0 = w * 512, lA1 = w * 512 + 2048;     // element offsets
  const int lB0 = 4096 + w * 512;                    // B region at +8KB

  f32x4 acc[8][4] = {};
  bf16x8 bfr[4], afr[8];
  const int sq8 = (qq ^ ((rl >> 1) & 3)) * 8;

#define SCB __builtin_amdgcn_sched_barrier(0)
#define BARR __builtin_amdgcn_s_barrier()
#define VMW(N) asm volatile("s_waitcnt vmcnt(" #N ")")

#define STG(BUF, KT)                                  \
  do {                                                \
    bf16* b_ = lds + (BUF) * 12288;                   \
    int ko_ = (KT) * 32;                              \
    gload16(gA0_ + ko_, b_ + lA0);                    \
    gload16(gA1_ + ko_, b_ + lA1);                    \
    gload16(gB_[0] + ko_, b_ + lB0);                  \
    gload16(gB_[1] + ko_, b_ + lB0 + 2048);           \
    gload16(gB_[2] + ko_, b_ + lB0 + 4096);           \
    gload16(gB_[3] + ko_, b_ + lB0 + 6144);           \
  } while (0)

#define COMP(BUF)                                                            \
  do {                                                                       \
    const bf16* ba_ = lds + (BUF) * 12288;                                   \
    const bf16* bb_ = ba_ + 4096;                                            \
    for (int j = 0; j < 4; j++)                                              \
      bfr[j] = *(const bf16x8*)(bb_ + (w * 64 + j * 16 + rl) * 32 + sq8);    \
    for (int mi = 0; mi < 8; mi++)                                           \
      afr[mi] = *(const bf16x8*)(ba_ + (mi * 16 + rl) * 32 + sq8);           \
    __builtin_amdgcn_s_setprio(1);                                           \
    for (int mi = 0; mi < 8; mi++)                                           \
      for (int j = 0; j < 4; j++)                                            \
        acc[mi][j] = mfma16(afr[mi], bfr[j], acc[mi][j]);                    \
    __builtin_amdgcn_s_setprio(0);                                           \
  } while (0)

  // prologue: stage kt = 0,1
  STG(0, 0);
  STG(1, 1);
  // main loop: kt = 0..29 (10 x unrolled-3); stage kt+2 = 2..31
#pragma unroll 1
  for (int t = 0; t < 10; t++) {
    const int kb = t * 3;
    VMW(6); SCB; BARR; SCB; STG(2, kb + 2); COMP(0);
    VMW(6); SCB; BARR; SCB; STG(0, kb + 3); COMP(1);
    VMW(6); SCB; BARR; SCB; STG(1, kb + 4); COMP(2);
  }
  // tail: kt = 30 (buf0), 31 (buf1)
  VMW(6); SCB; BARR; SCB; COMP(0);
  VMW(0); SCB; BARR; SCB; COMP(1);

#undef SCB
#undef BARR
#undef VMW
#undef STG
#undef COMP

  // epilogue
  if (z == 0) {
#pragma unroll
    for (int j = 0; j < 4; j++) {
      int gn = n0 + w * 64 + j * 16 + rl;
      float bb2 = bias[gn];
#pragma unroll
      for (int mi = 0; mi < 8; mi++) {
        int gm0 = m0 + mi * 16 + qq * 4;
#pragma unroll
        for (int r = 0; r < 4; r++)
          kh[(int64_t)(gm0 + r) * D_ + gn] = (bf16)(acc[mi][j][r] + bb2);
      }
    }
  } else {
#pragma unroll
    for (int j = 0; j < 4; j++) {
      int gn = n0 + w * 64 + j * 16 + rl;
      float bb2 = bias[gn];
#pragma unroll
      for (int mi = 0; mi < 8; mi++) {
        int gm0 = m0 + mi * 16 + qq * 4;
        f32x4 a = acc[mi][j];
        bf16x4 o = { (bf16)(a[0] + bb2), (bf16)(a[1] + bb2),
                     (bf16)(a[2] + bb2), (bf16)(a[3] + bb2) };
        *(bf16x4*)(vhT + (int64_t)gn * M_ + gm0) = o;
      }
    }
  }
}

// --------------------------- flash, no-max (L4) ----------------------------
__global__ __launch_bounds__(256, 2) void flash_kernel(
    const bf16* __restrict__ qh, const bf16* __restrict__ kh,
    const bf16* __restrict__ vhT, float* __restrict__ Oraw,
    float* __restrict__ lmat) {
  const int tid = threadIdx.x, lane = tid & 63, w = tid >> 6;
  const int rl = lane & 15, qq = lane >> 4;
  const int h = blockIdx.x >> 4, c = blockIdx.x & 15;
  __shared__ alignas(16) bf16 Plds[4 * 16 * 72];
  const bf16* qhp = qh + (int64_t)(w * 16 + rl) * D_ + h * 64 + qq * 8;
  bf16x8 aq0 = *(const bf16x8*)(qhp);
  bf16x8 aq1 = *(const bf16x8*)(qhp + 32);
  float lsum[4] = {0.f, 0.f, 0.f, 0.f};
  f32x4 acc_o[4] = {};
  bf16* pl = Plds + w * 1152;
  const bf16* khb = kh + (int64_t)(c * 512) * D_ + h * 64 + qq * 8;
  const bf16* vtb = vhT + (int64_t)(h * 64) * M_ + c * 512 + qq * 8;
  for (int nt = 0; nt < 8; nt++) {
    int mb = nt * 64;
    bf16x8 bk0[4], bk1[4], vv0[4], vv1[4];
#pragma unroll
    for (int j = 0; j < 4; j++) {
      const bf16* p = khb + (int64_t)(mb + j * 16 + rl) * D_;
      bk0[j] = *(const bf16x8*)(p);
      bk1[j] = *(const bf16x8*)(p + 32);
      const bf16* q = vtb + (int64_t)(j * 16 + rl) * M_ + mb;
      vv0[j] = *(const bf16x8*)(q);
      vv1[j] = *(const bf16x8*)(q + 32);
    }
    f32x4 s[4] = {};
#pragma unroll
    for (int j = 0; j < 4; j++) {
      s[j] = mfma16(aq0, bk0[j], s[j]);
      s[j] = mfma16(aq1, bk1[j], s[j]);
    }
#pragma unroll
    for (int j = 0; j < 4; j++)
#pragma unroll
      for (int r = 0; r < 4; r++) {
        float p = __expf(s[j][r]);
        lsum[r] += p;
        pl[(qq * 4 + r) * 72 + j * 16 + rl] = (bf16)p;
      }
    bf16x8 pa0 = *(const bf16x8*)(pl + rl * 72 + qq * 8);
    bf16x8 pa1 = *(const bf16x8*)(pl + rl * 72 + 32 + qq * 8);
#pragma unroll
    for (int j = 0; j < 4; j++) {
      acc_o[j] = mfma16(pa0, vv0[j], acc_o[j]);
      acc_o[j] = mfma16(pa1, vv1[j], acc_o[j]);
    }
  }
#pragma unroll
  for (int msk = 1; msk <= 8; msk <<= 1)
#pragma unroll
    for (int r = 0; r < 4; r++) lsum[r] += __shfl_xor(lsum[r], msk, 64);
#pragma unroll
  for (int j = 0; j < 4; j++)
#pragma unroll
    for (int r = 0; r < 4; r++)
      atomicAdd(&Oraw[(int64_t)(w * 16 + qq * 4 + r) * D_ + h * 64 + j * 16 + rl],
                acc_o[j][r]);
  if (rl == 0)
#pragma unroll
    for (int r = 0; r < 4; r++)
      atomicAdd(&lmat[h * 64 + w * 16 + qq * 4 + r], lsum[r]);
}

// ----------------------- split-K atomic tail stage -------------------------
// KIND: 0=bf16; 1=fp32; 2=relu(fp32); 3=sigmoid(p0)*p1; 4=p0*(1/l[h][m]).
struct Chunk { const void* p0; const void* p1; int ld; int kind; };
struct StageArgs { Chunk c[16]; };

template <int NKK>
__global__ __launch_bounds__(256) void tail_stage(
    StageArgs sa, const bf16* __restrict__ Bw, int ldb,
    float* __restrict__ Craw, int ldc) {
  const int n0 = blockIdx.x * 64, kc = blockIdx.y;
  const int bk0 = kc * NKK * 32;
  const Chunk ch = sa.c[kc];
  const int tid = threadIdx.x, lane = tid & 63, w = tid >> 6;
  const int rl = lane & 15, qq = lane >> 4;
  const int m = w * 16 + rl;
  const bf16* pb[4];
#pragma unroll
  for (int j = 0; j < 4; j++)
    pb[j] = Bw + (int64_t)(n0 + j * 16 + rl) * ldb + bk0 + qq * 8;
  f32x4 acc[4] = {};
#pragma unroll
  for (int kk = 0; kk < NKK; kk++) {
    bf16x8 af;
    if (ch.kind == 0) {
      af = *(const bf16x8*)((const bf16*)ch.p0 + (int64_t)m * ch.ld +
                            kk * 32 + qq * 8);
    } else {
      const float* p = (const float*)ch.p0 + (int64_t)m * ch.ld + kk * 32 + qq * 8;
      float4 u0 = *(const float4*)p;
      float4 u1 = *(const float4*)(p + 4);
      if (ch.kind == 2) {
        u0.x = fmaxf(u0.x, 0.f); u0.y = fmaxf(u0.y, 0.f);
        u0.z = fmaxf(u0.z, 0.f); u0.w = fmaxf(u0.w, 0.f);
        u1.x = fmaxf(u1.x, 0.f); u1.y = fmaxf(u1.y, 0.f);
        u1.z = fmaxf(u1.z, 0.f); u1.w = fmaxf(u1.w, 0.f);
      } else if (ch.kind == 3) {
        const float* pm = (const float*)ch.p1 + (int64_t)m * ch.ld + kk * 32 + qq * 8;
        float4 m0 = *(const float4*)pm;
        float4 m1 = *(const float4*)(pm + 4);
        u0.x = m0.x / (1.f + __expf(-u0.x)); u0.y = m0.y / (1.f + __expf(-u0.y));
        u0.z = m0.z / (1.f + __expf(-u0.z)); u0.w = m0.w / (1.f + __expf(-u0.w));
        u1.x = m1.x / (1.f + __expf(-u1.x)); u1.y = m1.y / (1.f + __expf(-u1.y));
        u1.z = m1.z / (1.f + __expf(-u1.z)); u1.w = m1.w / (1.f + __expf(-u1.w));
      } else if (ch.kind == 4) {
        int hidx = (bk0 + kk * 32) >> 6;
        float linv = 1.0f / ((const float*)ch.p1)[hidx * 64 + m];
        u0.x *= linv; u0.y *= linv; u0.z *= linv; u0.w *= linv;
        u1.x *= linv; u1.y *= linv; u1.z *= linv; u1.w *= linv;
      }
      af = (bf16x8){ (bf16)u0.x, (bf16)u0.y, (bf16)u0.z, (bf16)u0.w,
                     (bf16)u1.x, (bf16)u1.y, (bf16)u1.z, (bf16)u1.w };
    }
    bf16x8 bf_[4];
#pragma unroll
    for (int j = 0; j < 4; j++) bf_[j] = *(const bf16x8*)(pb[j] + kk * 32);
#pragma unroll
    for (int j = 0; j < 4; j++) acc[j] = mfma16(af, bf_[j], acc[j]);
  }
#pragma unroll
  for (int j = 0; j < 4; j++) {
    int gn = n0 + j * 16 + rl;
#pragma unroll
    for (int r = 0; r < 4; r++) {
      int gm = w * 16 + qq * 4 + r;
      atomicAdd(&Craw[(int64_t)gm * ldc + gn], acc[j][r]);
    }
  }
}

// ------------------------------- launch ------------------------------------
extern "C" void kernel_launch(void* const* d_in, const int* in_sizes, int n_in,
                              void* d_out, int out_size, void* d_ws,
                              size_t ws_size, hipStream_t stream) {
  (void)in_sizes; (void)n_in; (void)out_size;
  const float* x    = (const float*)d_in[0];
  const float* mk   = (const float*)d_in[1];
  const float* mv   = (const float*)d_in[2];
  const float* Wq   = (const float*)d_in[3];
  const float* bq   = (const float*)d_in[4];
  const float* Wk   = (const float*)d_in[5];
  const float* bk   = (const float*)d_in[6];
  const float* Wv   = (const float*)d_in[7];
  const float* bv   = (const float*)d_in[8];
  const float* inw  = (const float*)d_in[9];
  const float* inb  = (const float*)d_in[10];
  const float* outw = (const float*)d_in[11];
  const float* outb = (const float*)d_in[12];
  const float* gW1  = (const float*)d_in[13];
  const float* gb1  = (const float*)d_in[14];
  const float* gW2  = (const float*)d_in[15];
  const float* gb2  = (const float*)d_in[16];
  const float* iW1  = (const float*)d_in[17];
  const float* ib1  = (const float*)d_in[18];
  const float* iW2  = (const float*)d_in[19];
  const float* ib2  = (const float*)d_in[20];

  char* ws = (char*)d_ws;
  size_t off = 0;
  auto alloc = [&](size_t bytes) {
    char* p = ws + off;
    off += (bytes + 255) & ~(size_t)255;
    return p;
  };
  bf16* mkmv  = (bf16*)alloc((size_t)2 * M_ * D_ * 2);
  bf16* inpj  = (bf16*)alloc((size_t)3 * D_ * D_ * 2);
  bf16* WT    = (bf16*)alloc((size_t)3 * D_ * D_ * 2);
  bf16* Wc    = (bf16*)alloc((size_t)3 * D_ * D_ * 2);
  float* bc   = (float*)alloc(3 * D_ * 4);
  bf16* xbf   = (bf16*)alloc((size_t)B_ * D_ * 2);
  bf16* qh    = (bf16*)alloc((size_t)B_ * D_ * 2);
  bf16* kh    = (bf16*)alloc((size_t)M_ * D_ * 2);
  bf16* vhT   = (bf16*)alloc((size_t)M_ * D_ * 2);
  float* Oraw = (float*)alloc((size_t)B_ * D_ * 4);
  float* lmat = (float*)alloc((size_t)H_ * B_ * 4);
  float* msR  = (float*)alloc((size_t)B_ * D_ * 4);
  float* g1R  = (float*)alloc((size_t)B_ * D_ * 4);
  float* gateR= (float*)alloc((size_t)B_ * D_ * 4);
  float* h1R  = (float*)alloc((size_t)B_ * 2 * D_ * 4);
  bf16* gW1b  = (bf16*)alloc((size_t)D_ * 2 * D_ * 2);
  bf16* gW2b  = (bf16*)alloc((size_t)D_ * D_ * 2);
  bf16* iW1b  = (bf16*)alloc((size_t)2 * D_ * 2 * D_ * 2);
  bf16* iW2b  = (bf16*)alloc((size_t)D_ * 2 * D_ * 2);
  bf16* outwb = (bf16*)alloc((size_t)D_ * D_ * 2);
  if (ws_size < off) return;

  // L1: prep  (cvt ends in BLOCK units of 8192 floats)
  PrepArgs pa;
  pa.d[0] = { mk,   mkmv,           1024 };
  pa.d[1] = { mv,   mkmv + M_ * D_, 2048 };
  pa.d[2] = { inw,  inpj,           2432 };
  pa.d[3] = { gW1,  gW1b,           2688 };
  pa.d[4] = { gW2,  gW2b,           2816 };
  pa.d[5] = { iW1,  iW1b,           3328 };
  pa.d[6] = { iW2,  iW2b,           3584 };
  pa.d[7] = { outw, outwb,          3712 };
  pa.d[8] = { x,    xbf,            3720 };
  pa.Wq = Wq; pa.Wk = Wk; pa.Wv = Wv; pa.inw = inw; pa.inb = inb;
  pa.bq = bq; pa.bk = bk; pa.bv = bv;
  pa.outb = outb; pa.gb1 = gb1; pa.gb2 = gb2; pa.ib1 = ib1; pa.ib2 = ib2;
  pa.WT = WT; pa.bc = bc; pa.msR = msR; pa.g1R = g1R; pa.gateR = gateR;
  pa.h1R = h1R; pa.out = (float*)d_out; pa.Oraw = Oraw; pa.lmat = lmat;
  prep_kernel<<<dim3(8008), 256, 0, stream>>>(pa);

  // L2: Wc_z = Wi_z @ W_z
  gemm_big<<<dim3(8, 8, 3), 256, 0, stream>>>(
      inpj, D_, (int64_t)D_ * D_, WT, D_, (int64_t)D_ * D_,
      Wc, D_, (int64_t)D_ * D_, D_);

  // L3: kh / vhT via 128x256 2-per-CU kernel (+ qh thin blocks at tail)
  hipFuncSetAttribute((const void*)gemm_kv,
                      hipFuncAttributeMaxDynamicSharedMemorySize, 73728);
  gemm_kv<<<dim3(528), dim3(256), 73728, stream>>>(
      mkmv, Wc, bc, kh, vhT, xbf, Wc, qh, bc);

  // L4: flash partials -> atomic Oraw / lmat
  flash_kernel<<<dim3(256), 256, 0, stream>>>(qh, kh, vhT, Oraw, lmat);

  // L5 S1: msR += (Oraw/l) @ outwb^T   grid (16 n, 8 kc of 128)
  StageArgs s1;
  for (int kc = 0; kc < 8; kc++) s1.c[kc] = { Oraw + kc * 128, lmat, D_, 4 };
  tail_stage<4><<<dim3(16, 8), 256, 0, stream>>>(s1, outwb, D_, msR, D_);

  // L6 S2: g1R += [x | msR] @ gW1^T    grid (16, 16 kc of 128, K=2048)
  StageArgs s2;
  for (int kc = 0; kc < 8; kc++)  s2.c[kc] = { xbf + kc * 128, nullptr, D_, 0 };
  for (int kc = 8; kc < 16; kc++) s2.c[kc] = { msR + (kc - 8) * 128, nullptr, D_, 1 };
  tail_stage<4><<<dim3(16, 16), 256, 0, stream>>>(s2, gW1b, 2 * D_, g1R, D_);

  // L7 S3: gateR += relu(g1R) @ gW2^T  grid (16, 8)
  StageArgs s3;
  for (int kc = 0; kc < 8; kc++) s3.c[kc] = { g1R + kc * 128, nullptr, D_, 2 };
  tail_stage<4><<<dim3(16, 8), 256, 0, stream>>>(s3, gW2b, D_, gateR, D_);

  // L8 S4: h1R += [x | sig(gateR)*msR] @ iW1^T  grid (32, 16)
  StageArgs s4;
  for (int kc = 0; kc < 8; kc++)  s4.c[kc] = { xbf + kc * 128, nullptr, D_, 0 };
  for (int kc = 8; kc < 16; kc++)
    s4.c[kc] = { gateR + (kc - 8) * 128, msR + (kc - 8) * 128, D_, 3 };
  tail_stage<4><<<dim3(32, 16), 256, 0, stream>>>(s4, iW1b, 2 * D_, h1R, 2 * D_);

  // L9 S5: out += relu(h1R) @ iW2^T    grid (16, 16, K=2048)
  StageArgs s5;
  for (int kc = 0; kc < 16; kc++) s5.c[kc] = { h1R + kc * 128, nullptr, 2 * D_, 2 };
  tail_stage<4><<<dim3(16, 16), 256, 0, stream>>>(s5, iW2b, 2 * D_,
                                                  (float*)d_out, D_);
}

// Round 7
// 330.822 us; speedup vs baseline: 1.6708x; 1.0610x over previous
//
#include <hip/hip_runtime.h>
#include <hip/hip_bf16.h>
#include <stdint.h>

// ---------------------------------------------------------------------------
// AstrocyteMemoryModule r14: 9 launches.
//  L1 prep-A: ONLY what L2/L3 need: inpj+x cvt, W^T (q,k,v), combined bias,
//      accum bias-init, O/l zero. (~57 MB traffic)
//  L2' gemm_bigc: Wc = Wi@W (192 GEMM blocks, grid-FIRST) + 3328 cvt blocks
//      (mk, mv, gW1, gW2, iW1, iW2, outw fp32->bf16, 128B/thread) riding the
//      idle CUs/memory pipes. Overlap replaces ~35 us of serial prep.
//  L3 gemm256 (r10 revert - best measured L3 @63-65us): 256^2 phase-split
//      1/CU pipeline + thin qh blocks at grid tail.
//  L4 flash (no-max exp; atomicAdd unnormalized O partials + row-sums l)
//  L5-L9 tail stages: split-K atomic GEMMs.
//  History: 4 L3 schedules all land 63-68us (shape plateau) - stop there.
// ---------------------------------------------------------------------------

typedef __bf16 bf16;
typedef __bf16 bf16x4 __attribute__((ext_vector_type(4)));
typedef __bf16 bf16x8 __attribute__((ext_vector_type(8)));
typedef float f32x4 __attribute__((ext_vector_type(4)));

#define D_ 1024
#define M_ 8192
#define B_ 64
#define H_ 16

static __device__ __forceinline__ void gload16(const void* g, void* l) {
  __builtin_amdgcn_global_load_lds(
      (const __attribute__((address_space(1))) void*)g,
      (__attribute__((address_space(3))) void*)l, 16, 0, 0);
}

static __device__ __forceinline__ f32x4 mfma16(bf16x8 a, bf16x8 b, f32x4 c) {
  return __builtin_amdgcn_mfma_f32_16x16x32_bf16(a, b, c, 0, 0, 0);
}

// ----------------- 128B/thread block-uniform cvt helper --------------------
struct CvtD { const float* src; bf16* dst; int end; };  // end in BLOCK units

template <int N>
static __device__ __forceinline__ void cvt_block(const CvtD* d, int b, int tid) {
  CvtD dd = d[N - 1];
  int begin = N > 1 ? d[N - 2].end : 0;
#pragma unroll
  for (int t = N - 2; t >= 0; t--)
    if (b < d[t].end) { dd = d[t]; begin = t ? d[t - 1].end : 0; }
  int64_t i = (int64_t)(b - begin) * 8192 + tid * 32;
  const float* src = dd.src + i;
  bf16* dst = dd.dst + i;
  float4 v[8];
#pragma unroll
  for (int u = 0; u < 8; u++) v[u] = *(const float4*)(src + u * 4);
#pragma unroll
  for (int u = 0; u < 8; u++) {
    bf16x4 o = { (bf16)v[u].x, (bf16)v[u].y, (bf16)v[u].z, (bf16)v[u].w };
    *(bf16x4*)(dst + u * 4) = o;
  }
}

// ---------------- thin GEMM (M=64): C = A @ B^T, reg-prefetched -------------
template <int U, int KLEN, typename OutT>
__device__ __forceinline__ void thin_gemm(
    const bf16* __restrict__ A, int lda,
    const bf16* __restrict__ Bm, int ldb,
    OutT* __restrict__ C, int ldc,
    const float* __restrict__ bias, float scale) {
  const int tid = threadIdx.x, lane = tid & 63, w = tid >> 6;
  const int rl = lane & 15, qq = lane >> 4;
  const bf16* pa = A + (int64_t)(w * 16 + rl) * lda + qq * 8;
  const bf16* pb[4];
  pb[0] = Bm + (int64_t)rl * ldb + qq * 8;
  pb[1] = pb[0] + (int64_t)16 * ldb;
  pb[2] = pb[0] + (int64_t)32 * ldb;
  pb[3] = pb[0] + (int64_t)48 * ldb;
  f32x4 acc[4] = {};
  bf16x8 av[2][U], bv[2][U][4];
#pragma unroll
  for (int u = 0; u < U; u++) {
    av[0][u] = *(const bf16x8*)(pa + u * 32);
#pragma unroll
    for (int j = 0; j < 4; j++)
      bv[0][u][j] = *(const bf16x8*)(pb[j] + u * 32);
  }
  constexpr int NI = KLEN / (32 * U);
#pragma unroll
  for (int it = 0; it < NI; it++) {
    const int cur = it & 1, nxt = cur ^ 1;
    if (it + 1 < NI) {
      int k = (it + 1) * 32 * U;
#pragma unroll
      for (int u = 0; u < U; u++) {
        av[nxt][u] = *(const bf16x8*)(pa + k + u * 32);
#pragma unroll
        for (int j = 0; j < 4; j++)
          bv[nxt][u][j] = *(const bf16x8*)(pb[j] + k + u * 32);
      }
    }
#pragma unroll
    for (int u = 0; u < U; u++)
#pragma unroll
      for (int j = 0; j < 4; j++)
        acc[j] = mfma16(av[cur][u], bv[cur][u][j], acc[j]);
  }
#pragma unroll
  for (int j = 0; j < 4; j++) {
    int gn = j * 16 + rl;
    float bb = bias ? bias[gn] : 0.0f;
#pragma unroll
    for (int r = 0; r < 4; r++) {
      int gm = w * 16 + qq * 4 + r;
      C[(int64_t)gm * ldc + gn] = (OutT)((acc[j][r] + bb) * scale);
    }
  }
}

// ----------------------------- prep-A (L1) ---------------------------------
// blocks: [0,392) cvt (inpj 384, xbf 8), [392,3464) W^T (q,k,v),
//         [3464,4232) bias-combine, [4232,4616) accum bias-init,
//         [4616,4680) O/l zero
struct PrepArgs {
  CvtD d[2];
  const float *Wq, *Wk, *Wv, *inw, *inb, *bq, *bk, *bv;
  const float *outb, *gb1, *gb2, *ib1, *ib2;
  bf16* WT;
  float *bc, *msR, *g1R, *gateR, *h1R, *out, *Oraw, *lmat;
};

__global__ __launch_bounds__(256) void prep_kernel(PrepArgs a) {
  const int bx = blockIdx.x, tid = threadIdx.x;
  if (bx < 392) {
    cvt_block<2>(a.d, bx, tid);
  } else if (bx < 3464) {
    int t = bx - 392;
    int z = t >> 10, rem = t & 1023;   // z: 0=Wq 1=Wk 2=Wv
    const float* src = z == 0 ? a.Wq : z == 1 ? a.Wk : a.Wv;
    bf16* out = a.WT + (int64_t)z * D_ * D_;
    __shared__ bf16 tile[32][33];
    int tx = tid & 31, ty = tid >> 5;
    int r0 = (rem >> 5) * 32, c0 = (rem & 31) * 32;
#pragma unroll
    for (int i = 0; i < 32; i += 8)
      tile[ty + i][tx] = (bf16)src[(int64_t)(r0 + ty + i) * D_ + c0 + tx];
    __syncthreads();
#pragma unroll
    for (int i = 0; i < 32; i += 8)
      out[(int64_t)(c0 + ty + i) * D_ + r0 + tx] = tile[tx][ty + i];
  } else if (bx < 4232) {
    int t = bx - 3464;
    int w = tid >> 6, lane = tid & 63;
    int ng = t * 4 + w;  // [0, 3072)
    int z = ng >> 10;
    const float* Wi = a.inw + (int64_t)ng * D_;
    const float* b = z == 0 ? a.bq : z == 1 ? a.bk : a.bv;
    float acc = 0.f;
#pragma unroll
    for (int l = 0; l < D_; l += 64) acc += Wi[l + lane] * b[l + lane];
#pragma unroll
    for (int m = 32; m; m >>= 1) acc += __shfl_xor(acc, m, 64);
    if (lane == 0) a.bc[ng] = acc + a.inb[ng];
  } else if (bx < 4616) {
    int t = bx - 4232;            // [0, 384)
    int seg = t >> 6, row = t & 63;
    int n = tid * 4;              // [0, 1024)
    const float* b;
    float* dst;
    int bn = n;
    if (seg == 0)      { dst = a.msR   + row * 1024;        b = a.outb; }
    else if (seg == 1) { dst = a.g1R   + row * 1024;        b = a.gb1;  }
    else if (seg == 2) { dst = a.gateR + row * 1024;        b = a.gb2;  }
    else if (seg == 3) { dst = a.h1R   + row * 2048;        b = a.ib1;  }
    else if (seg == 4) { dst = a.h1R   + row * 2048 + 1024; b = a.ib1; bn = 1024 + n; }
    else               { dst = a.out   + row * 1024;        b = a.ib2;  }
    *(float4*)(dst + n) = *(const float4*)(b + bn);
  } else {
    int b = bx - 4616;            // [0, 64): O/l zero
    float4 z4 = {0.f, 0.f, 0.f, 0.f};
    *(float4*)(a.Oraw + b * 1024 + tid * 4) = z4;
    if (b < 16 && tid < 64) a.lmat[b * 64 + tid] = 0.f;
  }
}

// ------------- L2': Wc GEMM (192 blocks) + bulk cvt (3328 blocks) ----------
// bid [0,192): Wc_z = Wi_z @ W_z^T-form (128^2 tile, BK=32, K=1024).
// bid [192,3520): fp32->bf16 cvt of {mk, mv, gW1, gW2, iW1, iW2, outw} -
// independent of the GEMM inputs; fills idle CUs/memory pipes (GEMM is only
// 0.75 blocks/CU and latency-bound).
struct L2Args { CvtD d[7]; };

__global__ __launch_bounds__(256) void gemm_bigc(
    const bf16* __restrict__ A, const bf16* __restrict__ Bm,
    bf16* __restrict__ C, L2Args ca) {
  const int bid = blockIdx.x, tid = threadIdx.x;
  if (bid >= 192) {
    cvt_block<7>(ca.d, bid - 192, tid);
    return;
  }
  const int z = bid >> 6, r = bid & 63;
  const int m0 = (r >> 3) * 128, n0 = (r & 7) * 128;
  A += (int64_t)z * D_ * D_; Bm += (int64_t)z * D_ * D_;
  __shared__ alignas(16) bf16 As[128 * 32];
  __shared__ alignas(16) bf16 Bs[128 * 32];
  const int lane = tid & 63, w = tid >> 6;
  const int wm = (w & 1) * 64, wn = (w >> 1) * 64;
  const int rl = lane & 15, qq = lane >> 4;
  f32x4 acc[4][4] = {};

  int c0 = w * 64 + lane, c1 = (4 + w) * 64 + lane;
  int ra0 = c0 >> 2, qa0 = (c0 & 3) ^ ((ra0 >> 1) & 3);
  int ra1 = c1 >> 2, qa1 = (c1 & 3) ^ ((ra1 >> 1) & 3);
  const bf16* gA0 = A + (int64_t)(m0 + ra0) * D_ + qa0 * 8;
  const bf16* gA1 = A + (int64_t)(m0 + ra1) * D_ + qa1 * 8;
  const bf16* gB0 = Bm + (int64_t)(n0 + ra0) * D_ + qa0 * 8;
  const bf16* gB1 = Bm + (int64_t)(n0 + ra1) * D_ + qa1 * 8;
  bf16* lA0 = As + w * 512;
  bf16* lA1 = As + (4 + w) * 512;
  bf16* lB0 = Bs + w * 512;
  bf16* lB1 = Bs + (4 + w) * 512;

  for (int k0 = 0; k0 < D_; k0 += 32) {
    __syncthreads();
    gload16(gA0 + k0, lA0);
    gload16(gA1 + k0, lA1);
    gload16(gB0 + k0, lB0);
    gload16(gB1 + k0, lB1);
    __syncthreads();
    bf16x8 af[4], bb[4];
#pragma unroll
    for (int i = 0; i < 4; i++) {
      int rr = wm + i * 16 + rl;
      af[i] = *(const bf16x8*)(As + rr * 32 + (qq ^ ((rr >> 1) & 3)) * 8);
    }
#pragma unroll
    for (int j = 0; j < 4; j++) {
      int rr = wn + j * 16 + rl;
      bb[j] = *(const bf16x8*)(Bs + rr * 32 + (qq ^ ((rr >> 1) & 3)) * 8);
    }
#pragma unroll
    for (int i = 0; i < 4; i++)
#pragma unroll
      for (int j = 0; j < 4; j++)
        acc[i][j] = mfma16(af[i], bb[j], acc[i][j]);
  }
  C += (int64_t)z * D_ * D_;
#pragma unroll
  for (int j = 0; j < 4; j++) {
    int gn = n0 + wn + j * 16 + rl;
#pragma unroll
    for (int i = 0; i < 4; i++) {
      int gm0 = m0 + wm + i * 16 + qq * 4;
#pragma unroll
      for (int r2 = 0; r2 < 4; r2++)
        C[(int64_t)(gm0 + r2) * D_ + gn] = (bf16)acc[i][j][r2];
    }
  }
}

// ----------------- L3: 256^2-tile phase-split GEMM (kh + vhT) --------------
// (r10 structure - best measured of 4 L3 variants: 63-65us)
__global__ __launch_bounds__(512) void gemm256(
    const bf16* __restrict__ A,    // mkmv (z=0: mk, z=1: mv)
    const bf16* __restrict__ Wc,   // +D*D = Wc_k, +2D*D = Wc_v
    const float* __restrict__ bc,  // combined bias; +D = bik, +2D = biv
    bf16* __restrict__ kh, bf16* __restrict__ vhT,
    const bf16* __restrict__ qA, const bf16* __restrict__ qB,
    bf16* __restrict__ qC, const float* __restrict__ qbias) {
  extern __shared__ __align__(16) bf16 lds[];  // 4 * (8192 A + 8192 B) bf16
  const int bid = blockIdx.x;
  if (bid >= 256) {  // thin qh blocks at grid tail
    if (threadIdx.x < 256) {
      int n0q = (bid - 256) * 64;
      thin_gemm<2, 1024, bf16>(qA, D_, qB + (int64_t)n0q * D_, D_,
                               qC + n0q, D_, qbias + n0q, 0.125f);
    }
    return;
  }
  const int lin = bid;
  const int xcd = lin & 7, s = lin >> 3;
  const int z = xcd >> 2;
  const int m0 = ((xcd & 3) * 8 + (s >> 2)) * 256;
  const int n0 = (s & 3) * 256;
  const bf16* Ab = A + (int64_t)z * M_ * D_;
  const bf16* Bb = Wc + (int64_t)(z + 1) * D_ * D_;
  const float* bias = bc + (z + 1) * D_;

  const int tid = threadIdx.x, lane = tid & 63, w = tid >> 6;
  const int rl = lane & 15, qq = lane >> 4;
  const int wr = w >> 2, wcn = w & 3;

  const int ci0 = w * 128 + lane, ci1 = ci0 + 64;
  const int ra0 = ci0 >> 2, ca0 = (ci0 & 3) ^ ((ra0 >> 1) & 3);
  const int ra1 = ci1 >> 2, ca1 = (ci1 & 3) ^ ((ra1 >> 1) & 3);
  const bf16* gA0 = Ab + (int64_t)(m0 + ra0) * D_ + ca0 * 8;
  const bf16* gA1 = Ab + (int64_t)(m0 + ra1) * D_ + ca1 * 8;
  const bf16* gB0 = Bb + (int64_t)(n0 + ra0) * D_ + ca0 * 8;
  const bf16* gB1 = Bb + (int64_t)(n0 + ra1) * D_ + ca1 * 8;
  const int lA0 = w * 1024, lA1 = lA0 + 512;

  f32x4 acc[8][4] = {};
  bf16x8 bfr[4], afr[4];
  const int sq8 = (qq ^ ((rl >> 1) & 3)) * 8;

#define SCB __builtin_amdgcn_sched_barrier(0)
#define BARR __builtin_amdgcn_s_barrier()
#define VMW(N) asm volatile("s_waitcnt vmcnt(" #N ")")

#define STAGE_FULL(BUF, KT)                          \
  do {                                               \
    bf16* bse_ = lds + (BUF) * 16384;                \
    gload16(gA0 + (KT) * 32, bse_ + lA0);            \
    gload16(gA1 + (KT) * 32, bse_ + lA1);            \
    gload16(gB0 + (KT) * 32, bse_ + 8192 + lA0);     \
    gload16(gB1 + (KT) * 32, bse_ + 8192 + lA1);     \
  } while (0)

#define PH_A(BUF, DOSTAGE, SKT)                                              \
  do {                                                                       \
    const bf16* ba_ = lds + (BUF) * 16384;                                   \
    const bf16* bb_ = ba_ + 8192;                                            \
    for (int j = 0; j < 4; j++)                                              \
      bfr[j] = *(const bf16x8*)(bb_ + (wcn * 64 + j * 16 + rl) * 32 + sq8);  \
    for (int mi = 0; mi < 4; mi++)                                           \
      afr[mi] = *(const bf16x8*)(ba_ + (wr * 128 + mi * 16 + rl) * 32 + sq8);\
    if (DOSTAGE) {                                                           \
      bf16* bse_ = lds + ((SKT) & 3) * 16384;                                \
      gload16(gA0 + (SKT) * 32, bse_ + lA0);                                 \
      gload16(gA1 + (SKT) * 32, bse_ + lA1);                                 \
    }                                                                        \
    SCB; BARR; SCB;                                                          \
    __builtin_amdgcn_s_setprio(1);                                           \
    for (int mi = 0; mi < 4; mi++)                                           \
      for (int j = 0; j < 4; j++)                                            \
        acc[mi][j] = mfma16(afr[mi], bfr[j], acc[mi][j]);                    \
    __builtin_amdgcn_s_setprio(0);                                           \
    SCB; BARR; SCB;                                                          \
  } while (0)

#define PH_B(BUF, DOSTAGE, SKT, VMSTMT)                                      \
  do {                                                                       \
    const bf16* ba_ = lds + (BUF) * 16384;                                   \
    for (int mi = 0; mi < 4; mi++)                                           \
      afr[mi] =                                                              \
          *(const bf16x8*)(ba_ + (wr * 128 + (mi + 4) * 16 + rl) * 32 + sq8);\
    if (DOSTAGE) {                                                           \
      bf16* bse_ = lds + ((SKT) & 3) * 16384;                                \
      gload16(gB0 + (SKT) * 32, bse_ + 8192 + lA0);                          \
      gload16(gB1 + (SKT) * 32, bse_ + 8192 + lA1);                          \
    }                                                                        \
    VMSTMT;                                                                  \
    SCB; BARR; SCB;                                                          \
    __builtin_amdgcn_s_setprio(1);                                           \
    for (int mi = 0; mi < 4; mi++)                                           \
      for (int j = 0; j < 4; j++)                                            \
        acc[mi + 4][j] = mfma16(afr[mi], bfr[j], acc[mi + 4][j]);            \
    __builtin_amdgcn_s_setprio(0);                                           \
    SCB; BARR; SCB;                                                          \
  } while (0)

  STAGE_FULL(0, 0);
  STAGE_FULL(1, 1);
  STAGE_FULL(2, 2);
  VMW(8);
  SCB; BARR; SCB;

#pragma unroll 1
  for (int t = 0; t < 7; t++) {
    const int kb = t * 4;
    PH_A(0, 1, kb + 3); PH_B(0, 1, kb + 3, VMW(8));
    PH_A(1, 1, kb + 4); PH_B(1, 1, kb + 4, VMW(8));
    PH_A(2, 1, kb + 5); PH_B(2, 1, kb + 5, VMW(8));
    PH_A(3, 1, kb + 6); PH_B(3, 1, kb + 6, VMW(8));
  }
  PH_A(0, 1, 31); PH_B(0, 1, 31, VMW(8));
  PH_A(1, 0, 0);  PH_B(1, 0, 0, VMW(4));
  PH_A(2, 0, 0);  PH_B(2, 0, 0, VMW(0));
  PH_A(3, 0, 0);  PH_B(3, 0, 0, (void)0);

#undef SCB
#undef BARR
#undef VMW
#undef STAGE_FULL
#undef PH_A
#undef PH_B

  if (z == 0) {
#pragma unroll
    for (int j = 0; j < 4; j++) {
      int gn = n0 + wcn * 64 + j * 16 + rl;
      float bb2 = bias[gn];
#pragma unroll
      for (int mi = 0; mi < 8; mi++) {
        int gm0 = m0 + wr * 128 + mi * 16 + qq * 4;
#pragma unroll
        for (int r = 0; r < 4; r++)
          kh[(int64_t)(gm0 + r) * D_ + gn] = (bf16)(acc[mi][j][r] + bb2);
      }
    }
  } else {
#pragma unroll
    for (int j = 0; j < 4; j++) {
      int gn = n0 + wcn * 64 + j * 16 + rl;
      float bb2 = bias[gn];
#pragma unroll
      for (int mi = 0; mi < 8; mi++) {
        int gm0 = m0 + wr * 128 + mi * 16 + qq * 4;
        f32x4 a = acc[mi][j];
        bf16x4 o = { (bf16)(a[0] + bb2), (bf16)(a[1] + bb2),
                     (bf16)(a[2] + bb2), (bf16)(a[3] + bb2) };
        *(bf16x4*)(vhT + (int64_t)gn * M_ + gm0) = o;
      }
    }
  }
}

// --------------------------- flash, no-max (L4) ----------------------------
__global__ __launch_bounds__(256, 2) void flash_kernel(
    const bf16* __restrict__ qh, const bf16* __restrict__ kh,
    const bf16* __restrict__ vhT, float* __restrict__ Oraw,
    float* __restrict__ lmat) {
  const int tid = threadIdx.x, lane = tid & 63, w = tid >> 6;
  const int rl = lane & 15, qq = lane >> 4;
  const int h = blockIdx.x >> 4, c = blockIdx.x & 15;
  __shared__ alignas(16) bf16 Plds[4 * 16 * 72];
  const bf16* qhp = qh + (int64_t)(w * 16 + rl) * D_ + h * 64 + qq * 8;
  bf16x8 aq0 = *(const bf16x8*)(qhp);
  bf16x8 aq1 = *(const bf16x8*)(qhp + 32);
  float lsum[4] = {0.f, 0.f, 0.f, 0.f};
  f32x4 acc_o[4] = {};
  bf16* pl = Plds + w * 1152;
  const bf16* khb = kh + (int64_t)(c * 512) * D_ + h * 64 + qq * 8;
  const bf16* vtb = vhT + (int64_t)(h * 64) * M_ + c * 512 + qq * 8;
  for (int nt = 0; nt < 8; nt++) {
    int mb = nt * 64;
    bf16x8 bk0[4], bk1[4], vv0[4], vv1[4];
#pragma unroll
    for (int j = 0; j < 4; j++) {
      const bf16* p = khb + (int64_t)(mb + j * 16 + rl) * D_;
      bk0[j] = *(const bf16x8*)(p);
      bk1[j] = *(const bf16x8*)(p + 32);
      const bf16* q = vtb + (int64_t)(j * 16 + rl) * M_ + mb;
      vv0[j] = *(const bf16x8*)(q);
      vv1[j] = *(const bf16x8*)(q + 32);
    }
    f32x4 s[4] = {};
#pragma unroll
    for (int j = 0; j < 4; j++) {
      s[j] = mfma16(aq0, bk0[j], s[j]);
      s[j] = mfma16(aq1, bk1[j], s[j]);
    }
#pragma unroll
    for (int j = 0; j < 4; j++)
#pragma unroll
      for (int r = 0; r < 4; r++) {
        float p = __expf(s[j][r]);
        lsum[r] += p;
        pl[(qq * 4 + r) * 72 + j * 16 + rl] = (bf16)p;
      }
    bf16x8 pa0 = *(const bf16x8*)(pl + rl * 72 + qq * 8);
    bf16x8 pa1 = *(const bf16x8*)(pl + rl * 72 + 32 + qq * 8);
#pragma unroll
    for (int j = 0; j < 4; j++) {
      acc_o[j] = mfma16(pa0, vv0[j], acc_o[j]);
      acc_o[j] = mfma16(pa1, vv1[j], acc_o[j]);
    }
  }
#pragma unroll
  for (int msk = 1; msk <= 8; msk <<= 1)
#pragma unroll
    for (int r = 0; r < 4; r++) lsum[r] += __shfl_xor(lsum[r], msk, 64);
#pragma unroll
  for (int j = 0; j < 4; j++)
#pragma unroll
    for (int r = 0; r < 4; r++)
      atomicAdd(&Oraw[(int64_t)(w * 16 + qq * 4 + r) * D_ + h * 64 + j * 16 + rl],
                acc_o[j][r]);
  if (rl == 0)
#pragma unroll
    for (int r = 0; r < 4; r++)
      atomicAdd(&lmat[h * 64 + w * 16 + qq * 4 + r], lsum[r]);
}

// ----------------------- split-K atomic tail stage -------------------------
// KIND: 0=bf16; 1=fp32; 2=relu(fp32); 3=sigmoid(p0)*p1; 4=p0*(1/l[h][m]).
struct Chunk { const void* p0; const void* p1; int ld; int kind; };
struct StageArgs { Chunk c[16]; };

template <int NKK>
__global__ __launch_bounds__(256) void tail_stage(
    StageArgs sa, const bf16* __restrict__ Bw, int ldb,
    float* __restrict__ Craw, int ldc) {
  const int n0 = blockIdx.x * 64, kc = blockIdx.y;
  const int bk0 = kc * NKK * 32;
  const Chunk ch = sa.c[kc];
  const int tid = threadIdx.x, lane = tid & 63, w = tid >> 6;
  const int rl = lane & 15, qq = lane >> 4;
  const int m = w * 16 + rl;
  const bf16* pb[4];
#pragma unroll
  for (int j = 0; j < 4; j++)
    pb[j] = Bw + (int64_t)(n0 + j * 16 + rl) * ldb + bk0 + qq * 8;
  f32x4 acc[4] = {};
#pragma unroll
  for (int kk = 0; kk < NKK; kk++) {
    bf16x8 af;
    if (ch.kind == 0) {
      af = *(const bf16x8*)((const bf16*)ch.p0 + (int64_t)m * ch.ld +
                            kk * 32 + qq * 8);
    } else {
      const float* p = (const float*)ch.p0 + (int64_t)m * ch.ld + kk * 32 + qq * 8;
      float4 u0 = *(const float4*)p;
      float4 u1 = *(const float4*)(p + 4);
      if (ch.kind == 2) {
        u0.x = fmaxf(u0.x, 0.f); u0.y = fmaxf(u0.y, 0.f);
        u0.z = fmaxf(u0.z, 0.f); u0.w = fmaxf(u0.w, 0.f);
        u1.x = fmaxf(u1.x, 0.f); u1.y = fmaxf(u1.y, 0.f);
        u1.z = fmaxf(u1.z, 0.f); u1.w = fmaxf(u1.w, 0.f);
      } else if (ch.kind == 3) {
        const float* pm = (const float*)ch.p1 + (int64_t)m * ch.ld + kk * 32 + qq * 8;
        float4 m0 = *(const float4*)pm;
        float4 m1 = *(const float4*)(pm + 4);
        u0.x = m0.x / (1.f + __expf(-u0.x)); u0.y = m0.y / (1.f + __expf(-u0.y));
        u0.z = m0.z / (1.f + __expf(-u0.z)); u0.w = m0.w / (1.f + __expf(-u0.w));
        u1.x = m1.x / (1.f + __expf(-u1.x)); u1.y = m1.y / (1.f + __expf(-u1.y));
        u1.z = m1.z / (1.f + __expf(-u1.z)); u1.w = m1.w / (1.f + __expf(-u1.w));
      } else if (ch.kind == 4) {
        int hidx = (bk0 + kk * 32) >> 6;
        float linv = 1.0f / ((const float*)ch.p1)[hidx * 64 + m];
        u0.x *= linv; u0.y *= linv; u0.z *= linv; u0.w *= linv;
        u1.x *= linv; u1.y *= linv; u1.z *= linv; u1.w *= linv;
      }
      af = (bf16x8){ (bf16)u0.x, (bf16)u0.y, (bf16)u0.z, (bf16)u0.w,
                     (bf16)u1.x, (bf16)u1.y, (bf16)u1.z, (bf16)u1.w };
    }
    bf16x8 bf_[4];
#pragma unroll
    for (int j = 0; j < 4; j++) bf_[j] = *(const bf16x8*)(pb[j] + kk * 32);
#pragma unroll
    for (int j = 0; j < 4; j++) acc[j] = mfma16(af, bf_[j], acc[j]);
  }
#pragma unroll
  for (int j = 0; j < 4; j++) {
    int gn = n0 + j * 16 + rl;
#pragma unroll
    for (int r = 0; r < 4; r++) {
      int gm = w * 16 + qq * 4 + r;
      atomicAdd(&Craw[(int64_t)gm * ldc + gn], acc[j][r]);
    }
  }
}

// ------------------------------- launch ------------------------------------
extern "C" void kernel_launch(void* const* d_in, const int* in_sizes, int n_in,
                              void* d_out, int out_size, void* d_ws,
                              size_t ws_size, hipStream_t stream) {
  (void)in_sizes; (void)n_in; (void)out_size;
  const float* x    = (const float*)d_in[0];
  const float* mk   = (const float*)d_in[1];
  const float* mv   = (const float*)d_in[2];
  const float* Wq   = (const float*)d_in[3];
  const float* bq   = (const float*)d_in[4];
  const float* Wk   = (const float*)d_in[5];
  const float* bk   = (const float*)d_in[6];
  const float* Wv   = (const float*)d_in[7];
  const float* bv   = (const float*)d_in[8];
  const float* inw  = (const float*)d_in[9];
  const float* inb  = (const float*)d_in[10];
  const float* outw = (const float*)d_in[11];
  const float* outb = (const float*)d_in[12];
  const float* gW1  = (const float*)d_in[13];
  const float* gb1  = (const float*)d_in[14];
  const float* gW2  = (const float*)d_in[15];
  const float* gb2  = (const float*)d_in[16];
  const float* iW1  = (const float*)d_in[17];
  const float* ib1  = (const float*)d_in[18];
  const float* iW2  = (const float*)d_in[19];
  const float* ib2  = (const float*)d_in[20];

  char* ws = (char*)d_ws;
  size_t off = 0;
  auto alloc = [&](size_t bytes) {
    char* p = ws + off;
    off += (bytes + 255) & ~(size_t)255;
    return p;
  };
  bf16* mkmv  = (bf16*)alloc((size_t)2 * M_ * D_ * 2);
  bf16* inpj  = (bf16*)alloc((size_t)3 * D_ * D_ * 2);
  bf16* WT    = (bf16*)alloc((size_t)3 * D_ * D_ * 2);
  bf16* Wc    = (bf16*)alloc((size_t)3 * D_ * D_ * 2);
  float* bc   = (float*)alloc(3 * D_ * 4);
  bf16* xbf   = (bf16*)alloc((size_t)B_ * D_ * 2);
  bf16* qh    = (bf16*)alloc((size_t)B_ * D_ * 2);
  bf16* kh    = (bf16*)alloc((size_t)M_ * D_ * 2);
  bf16* vhT   = (bf16*)alloc((size_t)M_ * D_ * 2);
  float* Oraw = (float*)alloc((size_t)B_ * D_ * 4);
  float* lmat = (float*)alloc((size_t)H_ * B_ * 4);
  float* msR  = (float*)alloc((size_t)B_ * D_ * 4);
  float* g1R  = (float*)alloc((size_t)B_ * D_ * 4);
  float* gateR= (float*)alloc((size_t)B_ * D_ * 4);
  float* h1R  = (float*)alloc((size_t)B_ * 2 * D_ * 4);
  bf16* gW1b  = (bf16*)alloc((size_t)D_ * 2 * D_ * 2);
  bf16* gW2b  = (bf16*)alloc((size_t)D_ * D_ * 2);
  bf16* iW1b  = (bf16*)alloc((size_t)2 * D_ * 2 * D_ * 2);
  bf16* iW2b  = (bf16*)alloc((size_t)D_ * 2 * D_ * 2);
  bf16* outwb = (bf16*)alloc((size_t)D_ * D_ * 2);
  if (ws_size < off) return;

  // L1: prep-A (cvt ends in BLOCK units of 8192 floats)
  PrepArgs pa;
  pa.d[0] = { inw, inpj, 384 };
  pa.d[1] = { x,   xbf,  392 };
  pa.Wq = Wq; pa.Wk = Wk; pa.Wv = Wv; pa.inw = inw; pa.inb = inb;
  pa.bq = bq; pa.bk = bk; pa.bv = bv;
  pa.outb = outb; pa.gb1 = gb1; pa.gb2 = gb2; pa.ib1 = ib1; pa.ib2 = ib2;
  pa.WT = WT; pa.bc = bc; pa.msR = msR; pa.g1R = g1R; pa.gateR = gateR;
  pa.h1R = h1R; pa.out = (float*)d_out; pa.Oraw = Oraw; pa.lmat = lmat;
  prep_kernel<<<dim3(4680), 256, 0, stream>>>(pa);

  // L2': Wc GEMM (192 blocks first) + bulk cvt (3328 blocks)
  L2Args ca;
  ca.d[0] = { mk,   mkmv,           1024 };
  ca.d[1] = { mv,   mkmv + M_ * D_, 2048 };
  ca.d[2] = { gW1,  gW1b,           2304 };
  ca.d[3] = { gW2,  gW2b,           2432 };
  ca.d[4] = { iW1,  iW1b,           2944 };
  ca.d[5] = { iW2,  iW2b,           3200 };
  ca.d[6] = { outw, outwb,          3328 };
  gemm_bigc<<<dim3(3520), 256, 0, stream>>>(inpj, WT, Wc, ca);

  // L3: kh / vhT via phase-split 256^2 kernel (+ qh thin blocks at tail)
  hipFuncSetAttribute((const void*)gemm256,
                      hipFuncAttributeMaxDynamicSharedMemorySize, 131072);
  gemm256<<<dim3(272), dim3(512), 131072, stream>>>(
      mkmv, Wc, bc, kh, vhT, xbf, Wc, qh, bc);

  // L4: flash partials -> atomic Oraw / lmat
  flash_kernel<<<dim3(256), 256, 0, stream>>>(qh, kh, vhT, Oraw, lmat);

  // L5 S1: msR += (Oraw/l) @ outwb^T   grid (16 n, 8 kc of 128)
  StageArgs s1;
  for (int kc = 0; kc < 8; kc++) s1.c[kc] = { Oraw + kc * 128, lmat, D_, 4 };
  tail_stage<4><<<dim3(16, 8), 256, 0, stream>>>(s1, outwb, D_, msR, D_);

  // L6 S2: g1R += [x | msR] @ gW1^T    grid (16, 16 kc of 128, K=2048)
  StageArgs s2;
  for (int kc = 0; kc < 8; kc++)  s2.c[kc] = { xbf + kc * 128, nullptr, D_, 0 };
  for (int kc = 8; kc < 16; kc++) s2.c[kc] = { msR + (kc - 8) * 128, nullptr, D_, 1 };
  tail_stage<4><<<dim3(16, 16), 256, 0, stream>>>(s2, gW1b, 2 * D_, g1R, D_);

  // L7 S3: gateR += relu(g1R) @ gW2^T  grid (16, 8)
  StageArgs s3;
  for (int kc = 0; kc < 8; kc++) s3.c[kc] = { g1R + kc * 128, nullptr, D_, 2 };
  tail_stage<4><<<dim3(16, 8), 256, 0, stream>>>(s3, gW2b, D_, gateR, D_);

  // L8 S4: h1R += [x | sig(gateR)*msR] @ iW1^T  grid (32, 16)
  StageArgs s4;
  for (int kc = 0; kc < 8; kc++)  s4.c[kc] = { xbf + kc * 128, nullptr, D_, 0 };
  for (int kc = 8; kc < 16; kc++)
    s4.c[kc] = { gateR + (kc - 8) * 128, msR + (kc - 8) * 128, D_, 3 };
  tail_stage<4><<<dim3(32, 16), 256, 0, stream>>>(s4, iW1b, 2 * D_, h1R, 2 * D_);

  // L9 S5: out += relu(h1R) @ iW2^T    grid (16, 16, K=2048)
  StageArgs s5;
  for (int kc = 0; kc < 16; kc++) s5.c[kc] = { h1R + kc * 128, nullptr, 2 * D_, 2 };
  tail_stage<4><<<dim3(16, 16), 256, 0, stream>>>(s5, iW2b, 2 * D_,
                                                  (float*)d_out, D_);
}